// Round 18
// baseline (1031.183 us; speedup 1.0000x reference)
//
#include <hip/hip_runtime.h>
#include <math.h>

typedef unsigned short u16;
typedef unsigned int u32;
typedef _Float16 f16;
typedef f16 f16x8 __attribute__((ext_vector_type(8)));
typedef float f32x4 __attribute__((ext_vector_type(4)));

#define DIM 512
#define D_IN 4096
#define N_OBJS 2048
#define N_RELS 32768
#define N_OBJ_CLS 151
#define N_REL_CLS 51
#define EPSV 1e-5f

// d_out layout (floats)
#define OFF_HOBJ  0
#define OFF_HEDGE (N_OBJS*DIM)
#define OFF_OLOG  (OFF_HEDGE + N_RELS*DIM)
#define OFF_PLOG  (OFF_OLOG + N_OBJS*N_OBJ_CLS)
#define OFF_LBL   (OFF_PLOG + N_RELS*N_REL_CLS)
#define OFF_RI    (OFF_LBL + N_OBJS)

__device__ __forceinline__ float sigmoidf_(float x) { return 1.0f / (1.0f + expf(-x)); }
__device__ __forceinline__ u16 f2h_(float f) {
    union { f16 h; u16 u; } c; c.h = (f16)f; return c.u;
}
__device__ __forceinline__ float h2f_(u16 u) {
    union { f16 h; u16 u; } c; c.u = u; return (float)c.h;
}

// 8 fp32 -> packed f16 (uint4)
__device__ __forceinline__ void cvt8h1(const float* f, uint4& h) {
    u32 hh[8];
#pragma unroll
    for (int i = 0; i < 8; i++) hh[i] = f2h_(f[i]);
    h.x = hh[0] | (hh[1] << 16); h.y = hh[2] | (hh[3] << 16);
    h.z = hh[4] | (hh[5] << 16); h.w = hh[6] | (hh[7] << 16);
}
// 8 fp32 -> hi + lo (a ~= hi + lo)
__device__ __forceinline__ void cvt8h2(const float* f, uint4& h, uint4& l) {
    u32 hh[8], ll[8];
#pragma unroll
    for (int i = 0; i < 8; i++) {
        u16 x = f2h_(f[i]);
        hh[i] = x;
        ll[i] = f2h_(f[i] - h2f_(x));
    }
    h.x = hh[0] | (hh[1] << 16); h.y = hh[2] | (hh[3] << 16);
    h.z = hh[4] | (hh[5] << 16); h.w = hh[6] | (hh[7] << 16);
    l.x = ll[0] | (ll[1] << 16); l.y = ll[2] | (ll[3] << 16);
    l.z = ll[4] | (ll[5] << 16); l.w = ll[6] | (ll[7] << 16);
}

// LDS offset (u16 units) for (row, chunk8) in a [rows][32] tile, XOR-swizzled
__device__ __forceinline__ int swzo(int row, int c) {
    return row * 32 + ((c ^ ((row >> 1) & 3)) << 3);
}

// XCD-chunked bijective blockIdx swizzle (requires nwg % 8 == 0)
__device__ __forceinline__ int xcdswz(int orig, int nwg) {
    const int q = nwg >> 3;
    return (orig & 7) * q + (orig >> 3);
}

// async global->LDS, 16B per lane; LDS dest = wave-uniform base + lane*16
__device__ __forceinline__ void gload16(const void* g, void* l) {
    __builtin_amdgcn_global_load_lds(
        (const __attribute__((address_space(1))) void*)g,
        (__attribute__((address_space(3))) void*)l, 16, 0, 0);
}

// ---------------------------------------------------------------------------
// ONE-SHOT weight conversion: all 10 fp32 weight tensors -> f16 in a single
// launch. Segment boundaries are compile-time constants (quad = ushort4 units).
// ---------------------------------------------------------------------------
#define Q_BIG  (DIM * D_IN / 4)
#define Q_SQ   (DIM * DIM / 4)
#define Q_GRU  (3 * DIM * DIM / 4)
#define Q_OP   (N_OBJ_CLS * DIM / 4)
#define Q_PP   (N_REL_CLS * DIM / 4)
#define CV_C0  (Q_BIG)
#define CV_C1  (CV_C0 + Q_BIG)
#define CV_C2  (CV_C1 + Q_SQ)
#define CV_C3  (CV_C2 + Q_SQ)
#define CV_C4  (CV_C3 + Q_GRU)
#define CV_C5  (CV_C4 + Q_GRU)
#define CV_C6  (CV_C5 + Q_GRU)
#define CV_C7  (CV_C6 + Q_GRU)
#define CV_C8  (CV_C7 + Q_OP)
#define CV_C9  (CV_C8 + Q_PP)

__global__ __launch_bounds__(256) void convert_all(
    const float* __restrict__ s0, u16* __restrict__ d0,
    const float* __restrict__ s1, u16* __restrict__ d1,
    const float* __restrict__ s2, u16* __restrict__ d2,
    const float* __restrict__ s3, u16* __restrict__ d3,
    const float* __restrict__ s4, u16* __restrict__ d4,
    const float* __restrict__ s5, u16* __restrict__ d5,
    const float* __restrict__ s6, u16* __restrict__ d6,
    const float* __restrict__ s7, u16* __restrict__ d7,
    const float* __restrict__ s8, u16* __restrict__ d8,
    const float* __restrict__ s9, u16* __restrict__ d9)
{
    int i = blockIdx.x * 256 + threadIdx.x;
    if (i >= CV_C9) return;
    const float* src; u16* dst; int base;
    if      (i < CV_C0) { src = s0; dst = d0; base = 0; }
    else if (i < CV_C1) { src = s1; dst = d1; base = CV_C0; }
    else if (i < CV_C2) { src = s2; dst = d2; base = CV_C1; }
    else if (i < CV_C3) { src = s3; dst = d3; base = CV_C2; }
    else if (i < CV_C4) { src = s4; dst = d4; base = CV_C3; }
    else if (i < CV_C5) { src = s5; dst = d5; base = CV_C4; }
    else if (i < CV_C6) { src = s6; dst = d6; base = CV_C5; }
    else if (i < CV_C7) { src = s7; dst = d7; base = CV_C6; }
    else if (i < CV_C8) { src = s8; dst = d8; base = CV_C7; }
    else                { src = s9; dst = d9; base = CV_C8; }
    const int q = i - base;
    const float4 v = ((const float4*)src)[q];
    ((ushort4*)dst)[q] = make_ushort4(f2h_(v.x), f2h_(v.y), f2h_(v.z), f2h_(v.w));
}

// ---------------------------------------------------------------------------
// BODY: f16 GEMM, fp32 A split on the fly (AT terms), 1-deep A-reg prefetch,
// B f16 via global_load_lds. Caller provides LDS. BK=32, N = NX*128 exact.
// ---------------------------------------------------------------------------
template<bool RELU, int AT, bool WSPLIT>
__device__ __forceinline__ void gemm_a32_body(
    int id, u16* sAh, u16* sBh, u16* sAl,
    const float* __restrict__ A, const u16* __restrict__ Bhi,
    const float* __restrict__ bias, u16* __restrict__ Chi, u16* __restrict__ Clo,
    int NX, int K)
{
    const int m0 = (id / NX) * 128, n0 = (id % NX) * 128;
    const int N = NX * 128;
    const int t = threadIdx.x;
    const int wid = t >> 6, lane = t & 63;
    const int wm = (wid >> 1) * 64, wn = (wid & 1) * 64;
    const int lr = lane & 15, lk = lane >> 4;

    f32x4 acc[4][4] = {};

    const int sr = t >> 1;
    const int sc = (t & 1) * 2;
    const float* Ap = A + (size_t)(m0 + sr) * K + (t & 1) * 16;

    const int rB = (wid * 2) * 16 + (lane >> 2);
    const int cB = (lane & 3) ^ ((rB >> 1) & 3);
    const u16* Bp0 = Bhi + (size_t)(n0 + rB) * K + cB * 8;
    const u16* Bp1 = Bp0 + (size_t)16 * K;
    u16* Bd0 = &sBh[(wid * 2) * 512];
    u16* Bd1 = Bd0 + 512;

    float fv[16];
    *(float4*)&fv[0]  = *(const float4*)(Ap);
    *(float4*)&fv[4]  = *(const float4*)(Ap + 4);
    *(float4*)&fv[8]  = *(const float4*)(Ap + 8);
    *(float4*)&fv[12] = *(const float4*)(Ap + 12);

    for (int k0 = 0; k0 < K; k0 += 32) {
        uint4 ah0, ah1, al0, al1;
        if (AT == 2) { cvt8h2(fv, ah0, al0); cvt8h2(fv + 8, ah1, al1); }
        else         { cvt8h1(fv, ah0);      cvt8h1(fv + 8, ah1); }

        __syncthreads();                       // previous LDS reads complete
        gload16(Bp0 + k0, Bd0);
        gload16(Bp1 + k0, Bd1);
        *(uint4*)&sAh[swzo(sr, sc)]     = ah0;
        *(uint4*)&sAh[swzo(sr, sc + 1)] = ah1;
        if (AT == 2) {
            *(uint4*)&sAl[swzo(sr, sc)]     = al0;
            *(uint4*)&sAl[swzo(sr, sc + 1)] = al1;
        }
        asm volatile("s_waitcnt vmcnt(0)" ::: "memory");
        __syncthreads();

        const int kn = k0 + 32;
        if (kn < K) {
            *(float4*)&fv[0]  = *(const float4*)(Ap + kn);
            *(float4*)&fv[4]  = *(const float4*)(Ap + kn + 4);
            *(float4*)&fv[8]  = *(const float4*)(Ap + kn + 8);
            *(float4*)&fv[12] = *(const float4*)(Ap + kn + 12);
        }

        f16x8 ah[4], al[4], bh[4];
#pragma unroll
        for (int f = 0; f < 4; f++) {
            const int off = swzo(wm + f * 16 + lr, lk);
            ah[f] = *(const f16x8*)&sAh[off];
            if (AT == 2) al[f] = *(const f16x8*)&sAl[off];
            bh[f] = *(const f16x8*)&sBh[swzo(wn + f * 16 + lr, lk)];
        }
#pragma unroll
        for (int fm = 0; fm < 4; fm++)
#pragma unroll
            for (int fn = 0; fn < 4; fn++) {
                acc[fm][fn] = __builtin_amdgcn_mfma_f32_16x16x32_f16(ah[fm], bh[fn], acc[fm][fn], 0, 0, 0);
                if (AT == 2)
                    acc[fm][fn] = __builtin_amdgcn_mfma_f32_16x16x32_f16(al[fm], bh[fn], acc[fm][fn], 0, 0, 0);
            }
    }
#pragma unroll
    for (int fm = 0; fm < 4; fm++) {
        const int mrow = m0 + wm + fm * 16 + lk * 4;
#pragma unroll
        for (int fn = 0; fn < 4; fn++) {
            const int col = n0 + wn + fn * 16 + lr;
            const float bv = bias[col];
#pragma unroll
            for (int j = 0; j < 4; j++) {
                float v = acc[fm][fn][j] + bv;
                if (RELU) v = fmaxf(v, 0.0f);
                const u16 h = f2h_(v);
                Chi[(size_t)(mrow + j) * N + col] = h;
                if (WSPLIT) Clo[(size_t)(mrow + j) * N + col] = f2h_(v - h2f_(h));
            }
        }
    }
}

// FUSED enc1: ids [0,1024) = edge (AT1), ids [1024,1088) = obj (AT2, split out)
__global__ __launch_bounds__(256, 3) void enc1_both(
    const float* __restrict__ xp, const u16* __restrict__ pw,
    const float* __restrict__ pb, u16* __restrict__ tmpe,
    const float* __restrict__ xo, const u16* __restrict__ ow,
    const float* __restrict__ ob, u16* __restrict__ tmpoh, u16* __restrict__ tmpol)
{
    __shared__ u16 smem[3 * 4096];
    const int id = xcdswz(blockIdx.x, gridDim.x);
    if (id < 1024)
        gemm_a32_body<true, 1, false>(id, smem, smem + 4096, nullptr,
                                      xp, pw, pb, tmpe, nullptr, 4, D_IN);
    else
        gemm_a32_body<true, 2, true>(id - 1024, smem, smem + 4096, smem + 8192,
                                     xo, ow, ob, tmpoh, tmpol, 4, D_IN);
}

// ---------------------------------------------------------------------------
// BODY: f16 GEMM, A presplit (hi [+lo if AT=2]), B f16; all via gload_lds.
// BK=64. LDS: sA0=0, sA1=4096, sB0=8192, sB1=12288, [sL0=16384, sL1=20480].
// ---------------------------------------------------------------------------
template<int AT, bool WF32, bool WHI, bool WLO>
__device__ __forceinline__ void gemm_f16_body(
    int id, u16* smem,
    const u16* __restrict__ Ahi, const u16* __restrict__ Alo,
    const u16* __restrict__ Bhi, const float* __restrict__ bias,
    float* __restrict__ C32, u16* __restrict__ Chi, u16* __restrict__ Clo,
    int NX, int N, int ldc, int K)
{
    const int m0 = (id / NX) * 128, n0 = (id % NX) * 128;
    const int t = threadIdx.x;
    const int wid = t >> 6, lane = t & 63;
    const int wm = (wid >> 1) * 64, wn = (wid & 1) * 64;
    const int lr = lane & 15, lk = lane >> 4;

    f32x4 acc[4][4] = {};

    const int rr = (wid * 2) * 16 + (lane >> 2);
    const int cc = (lane & 3) ^ ((rr >> 1) & 3);
    const u16* pA0 = Ahi + (size_t)(m0 + rr) * K + cc * 8;
    const u16* pA1 = pA0 + (size_t)16 * K;
    const u16* pL0 = (AT == 2) ? Alo + (size_t)(m0 + rr) * K + cc * 8 : nullptr;
    const u16* pL1 = (AT == 2) ? pL0 + (size_t)16 * K : nullptr;
    const u16* pB0 = Bhi + (size_t)(n0 + rr) * K + cc * 8;
    const u16* pB1 = pB0 + (size_t)16 * K;
    const int bOff = (wid * 2) * 512;

    for (int k0 = 0; k0 < K; k0 += 64) {
        __syncthreads();
#pragma unroll
        for (int h = 0; h < 2; h++) {
            const int kk = k0 + h * 32;
            u16* sA_ = smem + h * 4096;
            u16* sB_ = smem + 8192 + h * 4096;
            gload16(pA0 + kk, sA_ + bOff);
            gload16(pA1 + kk, sA_ + bOff + 512);
            if (AT == 2) {
                u16* sL_ = smem + 16384 + h * 4096;
                gload16(pL0 + kk, sL_ + bOff);
                gload16(pL1 + kk, sL_ + bOff + 512);
            }
            gload16(pB0 + kk, sB_ + bOff);
            gload16(pB1 + kk, sB_ + bOff + 512);
        }
        asm volatile("s_waitcnt vmcnt(0)" ::: "memory");
        __syncthreads();

#pragma unroll
        for (int h = 0; h < 2; h++) {
            const u16* sA_ = smem + h * 4096;
            const u16* sB_ = smem + 8192 + h * 4096;
            const u16* sL_ = smem + 16384 + h * 4096;
            f16x8 ah[4], al[4], bh[4];
#pragma unroll
            for (int f = 0; f < 4; f++) {
                const int off = swzo(wm + f * 16 + lr, lk);
                ah[f] = *(const f16x8*)&sA_[off];
                if (AT == 2) al[f] = *(const f16x8*)&sL_[off];
                bh[f] = *(const f16x8*)&sB_[swzo(wn + f * 16 + lr, lk)];
            }
#pragma unroll
            for (int fm = 0; fm < 4; fm++)
#pragma unroll
                for (int fn = 0; fn < 4; fn++) {
                    acc[fm][fn] = __builtin_amdgcn_mfma_f32_16x16x32_f16(ah[fm], bh[fn], acc[fm][fn], 0, 0, 0);
                    if (AT == 2)
                        acc[fm][fn] = __builtin_amdgcn_mfma_f32_16x16x32_f16(al[fm], bh[fn], acc[fm][fn], 0, 0, 0);
                }
        }
    }
#pragma unroll
    for (int fm = 0; fm < 4; fm++) {
        const int mrow = m0 + wm + fm * 16 + lk * 4;
#pragma unroll
        for (int fn = 0; fn < 4; fn++) {
            const int col = n0 + wn + fn * 16 + lr;
            const float bv = bias[col];
#pragma unroll
            for (int j = 0; j < 4; j++) {
                const float v = acc[fm][fn][j] + bv;
                if (WF32 && col < N) C32[(size_t)(mrow + j) * ldc + col] = v;
                if (WHI) {
                    const u16 h = f2h_(v);
                    Chi[(size_t)(mrow + j) * (NX * 128) + col] = h;
                    if (WLO)
                        Clo[(size_t)(mrow + j) * (NX * 128) + col] = f2h_(v - h2f_(h));
                }
            }
        }
    }
}

// Standalone presplit GEMM kernels (enc2)
template<int AT, bool WF32, bool WHI, bool WLO>
__global__ __launch_bounds__(256, AT == 1 ? 4 : 3) void gemm_f16(
    const u16* __restrict__ Ahi, const u16* __restrict__ Alo,
    const u16* __restrict__ Bhi, const float* __restrict__ bias,
    float* __restrict__ C32, u16* __restrict__ Chi, u16* __restrict__ Clo,
    int NX, int N, int ldc, int K)
{
    __shared__ u16 smem[AT == 2 ? 6 * 4096 : 4 * 4096];
    const int id = xcdswz(blockIdx.x, gridDim.x);
    gemm_f16_body<AT, WF32, WHI, WLO>(id, smem, Ahi, Alo, Bhi, bias,
                                      C32, Chi, Clo, NX, N, ldc, K);
}

// FUSED classifiers: ids [0,256) = edge cls (AT1), [256,288) = obj cls (AT2)
__global__ __launch_bounds__(256, 3) void cls_both(
    const u16* __restrict__ hhe, const u16* __restrict__ pph,
    const float* __restrict__ ppb, float* __restrict__ plog,
    const u16* __restrict__ hhoh, const u16* __restrict__ hhol,
    const u16* __restrict__ oph, const float* __restrict__ opb,
    float* __restrict__ olog)
{
    __shared__ u16 smem[6 * 4096];
    const int id = xcdswz(blockIdx.x, gridDim.x);
    if (id < 256)
        gemm_f16_body<1, true, false, false>(id, smem, hhe, nullptr, pph, ppb,
                                             plog, nullptr, nullptr,
                                             1, N_REL_CLS, N_REL_CLS, DIM);
    else
        gemm_f16_body<2, true, false, false>(id - 256, smem, hhoh, hhol, oph, opb,
                                             olog, nullptr, nullptr,
                                             2, N_OBJ_CLS, N_OBJ_CLS, DIM);
}

// ---------------------------------------------------------------------------
// Plain merged edge GRU GEMM (chunks after the first): AT=1, 32KB LDS.
// ---------------------------------------------------------------------------
__global__ __launch_bounds__(256, 4) void gru_gemm_e(
    const u16* __restrict__ Xh, const u16* __restrict__ WiH,
    const float* __restrict__ bi, u16* __restrict__ gi,
    const u16* __restrict__ Hh, const u16* __restrict__ WhH,
    const float* __restrict__ bhs, u16* __restrict__ gh_)
{
    __shared__ u16 smem[4 * 4096];
    const int id = xcdswz(blockIdx.x, gridDim.x);
    const int part = id % 24;
    const int m0b = id / 24;
    const bool isH = part >= 12;
    const int nblk = part - (isH ? 12 : 0);
    gemm_f16_body<1, false, true, false>(m0b * 12 + nblk, smem,
        isH ? Hh : Xh, nullptr, isH ? WhH : WiH, isH ? bhs : bi,
        nullptr, isH ? gh_ : gi, nullptr, 12, 1536, 1536, DIM);
}

// ---------------------------------------------------------------------------
// FUSED GRU GEMM chunk-1: ids [0,nEdge) = edge (AT1) rows of chunk 1;
// ids [nEdge, nEdge+384) = obj (AT2). 48KB LDS (AT2 requirement).
// Hides the grid-starved 384-block obj GEMM under the big edge launch.
// ---------------------------------------------------------------------------
__global__ __launch_bounds__(256, 3) void gru_edge_obj(
    const u16* __restrict__ Xe, const u16* __restrict__ WeI,
    const float* __restrict__ beI, u16* __restrict__ geI,
    const u16* __restrict__ He, const u16* __restrict__ WeH,
    const float* __restrict__ beH, u16* __restrict__ geH,
    int nEdge,
    const u16* __restrict__ Xoh, const u16* __restrict__ Xol,
    const u16* __restrict__ WoI, const float* __restrict__ boI, u16* __restrict__ goI,
    const u16* __restrict__ Hoh, const u16* __restrict__ Hol,
    const u16* __restrict__ WoH, const float* __restrict__ boH, u16* __restrict__ goH)
{
    __shared__ u16 smem[6 * 4096];
    const int id = xcdswz(blockIdx.x, gridDim.x);
    if (id < nEdge) {
        const int part = id % 24;
        const int m0b = id / 24;
        const bool isH = part >= 12;
        const int nblk = part - (isH ? 12 : 0);
        gemm_f16_body<1, false, true, false>(m0b * 12 + nblk, smem,
            isH ? He : Xe, nullptr, isH ? WeH : WeI, isH ? beH : beI,
            nullptr, isH ? geH : geI, nullptr, 12, 1536, 1536, DIM);
    } else {
        const int oid = id - nEdge;
        const int part = oid % 24;
        const int m0b = oid / 24;
        const bool isH = part >= 12;
        const int nblk = part - (isH ? 12 : 0);
        gemm_f16_body<2, false, true, false>(m0b * 12 + nblk, smem,
            isH ? Hoh : Xoh, isH ? Hol : Xol, isH ? WoH : WoI, isH ? boH : boI,
            nullptr, isH ? goH : goI, nullptr, 12, 1536, 1536, DIM);
    }
}

// ---------------------------------------------------------------------------
// GRU combine: gi/gh f16 [R x 1536]; old h read from f16 shadow (hi [+lo]);
// writes shadow (hi [+lo]) and optionally the final f32 state.
// ---------------------------------------------------------------------------
__device__ __forceinline__ float gcomb(u16 ir, u16 iz, u16 in_, u16 hr, u16 hz,
                                       u16 hn, float h) {
    const float r = sigmoidf_(h2f_(ir) + h2f_(hr));
    const float z = sigmoidf_(h2f_(iz) + h2f_(hz));
    const float n = tanhf(h2f_(in_) + r * h2f_(hn));
    return (1.0f - z) * n + z * h;
}

template<bool WSPLIT, bool WF32>
__global__ __launch_bounds__(256) void gru_combine(
    const u16* __restrict__ gi, const u16* __restrict__ gh,
    u16* __restrict__ hh, u16* __restrict__ hl, float* __restrict__ H32, int R)
{
    const int idx = blockIdx.x * 256 + threadIdx.x;      // R*128 quads
    if (idx >= R * 128) return;
    const int r = idx >> 7, c4 = (idx & 127) * 4;
    const size_t gb = (size_t)r * 1536 + c4;
    const ushort4 ir4 = *(const ushort4*)&gi[gb];
    const ushort4 iz4 = *(const ushort4*)&gi[gb + 512];
    const ushort4 in4 = *(const ushort4*)&gi[gb + 1024];
    const ushort4 hr4 = *(const ushort4*)&gh[gb];
    const ushort4 hz4 = *(const ushort4*)&gh[gb + 512];
    const ushort4 hn4 = *(const ushort4*)&gh[gb + 1024];
    const size_t hb = (size_t)r * 512 + c4;
    const ushort4 hhi = *(const ushort4*)&hh[hb];
    float h0 = h2f_(hhi.x), h1 = h2f_(hhi.y), h2 = h2f_(hhi.z), h3 = h2f_(hhi.w);
    if (WSPLIT) {
        const ushort4 hlo = *(const ushort4*)&hl[hb];
        h0 += h2f_(hlo.x); h1 += h2f_(hlo.y); h2 += h2f_(hlo.z); h3 += h2f_(hlo.w);
    }
    float4 o;
    o.x = gcomb(ir4.x, iz4.x, in4.x, hr4.x, hz4.x, hn4.x, h0);
    o.y = gcomb(ir4.y, iz4.y, in4.y, hr4.y, hz4.y, hn4.y, h1);
    o.z = gcomb(ir4.z, iz4.z, in4.z, hr4.z, hz4.z, hn4.z, h2);
    o.w = gcomb(ir4.w, iz4.w, in4.w, hr4.w, hz4.w, hn4.w, h3);
    const ushort4 hi4 = make_ushort4(f2h_(o.x), f2h_(o.y), f2h_(o.z), f2h_(o.w));
    *(ushort4*)&hh[hb] = hi4;
    if (WSPLIT) {
        *(ushort4*)&hl[hb] = make_ushort4(
            f2h_(o.x - h2f_(hi4.x)), f2h_(o.y - h2f_(hi4.y)),
            f2h_(o.z - h2f_(hi4.z)), f2h_(o.w - h2f_(hi4.w)));
    }
    if (WF32) *(float4*)&H32[hb] = o;
}

// ---------------------------------------------------------------------------
// CSR build
// ---------------------------------------------------------------------------
__global__ __launch_bounds__(256) void count_int(const int* __restrict__ rel,
                                                 int* cs, int* co)
{
    const int e = blockIdx.x * 256 + threadIdx.x;
    atomicAdd(&cs[rel[2 * e]], 1);
    atomicAdd(&co[rel[2 * e + 1]], 1);
}

__global__ __launch_bounds__(256) void scan_off(const int* __restrict__ cs,
    const int* __restrict__ co, int* __restrict__ offs, int* __restrict__ offo)
{
    __shared__ int tmp[256];
    for (int arr = 0; arr < 2; arr++) {
        const int* c = arr ? co : cs;
        int* off = arr ? offo : offs;
        const int base = threadIdx.x * 8;
        int loc[8]; int s = 0;
#pragma unroll
        for (int j = 0; j < 8; j++) { loc[j] = c[base + j]; s += loc[j]; }
        tmp[threadIdx.x] = s;
        __syncthreads();
        for (int d = 1; d < 256; d <<= 1) {
            const int v = (threadIdx.x >= d) ? tmp[threadIdx.x - d] : 0;
            __syncthreads();
            tmp[threadIdx.x] += v;
            __syncthreads();
        }
        int p = tmp[threadIdx.x] - s;    // exclusive prefix
#pragma unroll
        for (int j = 0; j < 8; j++) { off[base + j] = p; p += loc[j]; }
        __syncthreads();
    }
}

__global__ __launch_bounds__(256) void fill_csr(const int* __restrict__ rel,
    int* curS, int* curO, const int* __restrict__ offs, const int* __restrict__ offo,
    int* __restrict__ listS, int* __restrict__ listO)
{
    const int e = blockIdx.x * 256 + threadIdx.x;
    const int s = rel[2 * e], o = rel[2 * e + 1];
    const int i = atomicAdd(&curS[s], 1);
    listS[offs[s] + i] = e;
    const int j = atomicAdd(&curO[o], 1);
    listO[offo[o] + j] = e;
}

// ---------------------------------------------------------------------------
// Gates + edge messages, one WAVE per edge (no barrier, no atomics).
// ---------------------------------------------------------------------------
__global__ __launch_bounds__(256) void gatepass(
    const u16* __restrict__ hho, const u16* __restrict__ hhe,
    const int* __restrict__ rel,
    const float* __restrict__ wsn, const float* __restrict__ bsn,
    const float* __restrict__ won, const float* __restrict__ bon,
    const float* __restrict__ wse, const float* __restrict__ bse,
    const float* __restrict__ woe, const float* __restrict__ boe,
    const int* __restrict__ cs, const int* __restrict__ co,
    u16* __restrict__ emh, float* __restrict__ af, float* __restrict__ ag)
{
    const int e = blockIdx.x * 4 + (threadIdx.x >> 6);
    const int lane = threadIdx.x & 63;
    const int s = rel[2 * e], o = rel[2 * e + 1];
    const int c = lane * 8;

    const uint4 hsu = *(const uint4*)&hho[(size_t)s * DIM + c];
    const uint4 hou = *(const uint4*)&hho[(size_t)o * DIM + c];
    const uint4 heu = *(const uint4*)&hhe[(size_t)e * DIM + c];
    float hs[8], ho[8], he[8];
    hs[0] = h2f_((u16)hsu.x); hs[1] = h2f_((u16)(hsu.x >> 16));
    hs[2] = h2f_((u16)hsu.y); hs[3] = h2f_((u16)(hsu.y >> 16));
    hs[4] = h2f_((u16)hsu.z); hs[5] = h2f_((u16)(hsu.z >> 16));
    hs[6] = h2f_((u16)hsu.w); hs[7] = h2f_((u16)(hsu.w >> 16));
    ho[0] = h2f_((u16)hou.x); ho[1] = h2f_((u16)(hou.x >> 16));
    ho[2] = h2f_((u16)hou.y); ho[3] = h2f_((u16)(hou.y >> 16));
    ho[4] = h2f_((u16)hou.z); ho[5] = h2f_((u16)(hou.z >> 16));
    ho[6] = h2f_((u16)hou.w); ho[7] = h2f_((u16)(hou.w >> 16));
    he[0] = h2f_((u16)heu.x); he[1] = h2f_((u16)(heu.x >> 16));
    he[2] = h2f_((u16)heu.y); he[3] = h2f_((u16)(heu.y >> 16));
    he[4] = h2f_((u16)heu.z); he[5] = h2f_((u16)(heu.z >> 16));
    he[6] = h2f_((u16)heu.w); he[7] = h2f_((u16)(heu.w >> 16));

    float p0 = 0.f, p1 = 0.f, p2 = 0.f, p3 = 0.f;
#pragma unroll
    for (int q = 0; q < 2; q++) {
        const float4 w0v = *(const float4*)&wsn[c + q * 4];
        const float4 w0e = *(const float4*)&wsn[DIM + c + q * 4];
        const float4 w1v = *(const float4*)&won[c + q * 4];
        const float4 w1e = *(const float4*)&won[DIM + c + q * 4];
        const float4 w2v = *(const float4*)&wse[c + q * 4];
        const float4 w2e = *(const float4*)&wse[DIM + c + q * 4];
        const float4 w3v = *(const float4*)&woe[c + q * 4];
        const float4 w3e = *(const float4*)&woe[DIM + c + q * 4];
        const float* s4 = &hs[q * 4];
        const float* o4 = &ho[q * 4];
        const float* e4 = &he[q * 4];
        p0 += s4[0]*w0v.x + s4[1]*w0v.y + s4[2]*w0v.z + s4[3]*w0v.w
            + e4[0]*w0e.x + e4[1]*w0e.y + e4[2]*w0e.z + e4[3]*w0e.w;
        p1 += o4[0]*w1v.x + o4[1]*w1v.y + o4[2]*w1v.z + o4[3]*w1v.w
            + e4[0]*w1e.x + e4[1]*w1e.y + e4[2]*w1e.z + e4[3]*w1e.w;
        p2 += s4[0]*w2v.x + s4[1]*w2v.y + s4[2]*w2v.z + s4[3]*w2v.w
            + e4[0]*w2e.x + e4[1]*w2e.y + e4[2]*w2e.z + e4[3]*w2e.w;
        p3 += o4[0]*w3v.x + o4[1]*w3v.y + o4[2]*w3v.z + o4[3]*w3v.w
            + e4[0]*w3e.x + e4[1]*w3e.y + e4[2]*w3e.z + e4[3]*w3e.w;
    }
#pragma unroll
    for (int off = 32; off; off >>= 1) {
        p0 += __shfl_xor(p0, off);
        p1 += __shfl_xor(p1, off);
        p2 += __shfl_xor(p2, off);
        p3 += __shfl_xor(p3, off);
    }
    const float gsn = sigmoidf_(p0 + bsn[0]);
    const float gon = sigmoidf_(p1 + bon[0]);
    const float gse = sigmoidf_(p2 + bse[0]);
    const float goe = sigmoidf_(p3 + boe[0]);

    if (lane == 0) {
        af[e] = 0.5f * gsn / ((float)cs[s] + EPSV);
        ag[e] = 0.5f * gon / ((float)co[o] + EPSV);
    }
    u16 em8[8];
#pragma unroll
    for (int j = 0; j < 8; j++)
        em8[j] = f2h_(0.5f * (gse * hs[j] + goe * ho[j]));
    *(uint4*)&emh[(size_t)e * DIM + c] = *(const uint4*)em8;
}

// ---------------------------------------------------------------------------
// Node-message gather (no atomics), reading f16 h_edge shadow.
// ---------------------------------------------------------------------------
__global__ __launch_bounds__(256) void gather_nm(
    const u16* __restrict__ hhe,
    const int* __restrict__ listS, const int* __restrict__ listO,
    const int* __restrict__ offs, const int* __restrict__ offo,
    const int* __restrict__ cs, const int* __restrict__ co,
    const float* __restrict__ af, const float* __restrict__ ag,
    u16* __restrict__ nmh, u16* __restrict__ nml)
{
    const int v = blockIdx.x * 4 + (threadIdx.x >> 6);
    const int lane = threadIdx.x & 63;
    const int c = lane * 8;

    float acc[8] = {};
#pragma unroll
    for (int side = 0; side < 2; side++) {
        const int* list = side ? listO : listS;
        const int b = side ? offo[v] : offs[v];
        const int n = side ? co[v] : cs[v];
        const float* coef = side ? ag : af;
        for (int i = 0; i < n; i++) {
            const int e = list[b + i];
            const float a = coef[e];
            const uint4 x = *(const uint4*)&hhe[(size_t)e * DIM + c];
            acc[0] += a * h2f_((u16)x.x); acc[1] += a * h2f_((u16)(x.x >> 16));
            acc[2] += a * h2f_((u16)x.y); acc[3] += a * h2f_((u16)(x.y >> 16));
            acc[4] += a * h2f_((u16)x.z); acc[5] += a * h2f_((u16)(x.z >> 16));
            acc[6] += a * h2f_((u16)x.w); acc[7] += a * h2f_((u16)(x.w >> 16));
        }
    }
    u16 hi8[8], lo8[8];
#pragma unroll
    for (int j = 0; j < 8; j++) {
        hi8[j] = f2h_(acc[j]);
        lo8[j] = f2h_(acc[j] - h2f_(hi8[j]));
    }
    *(uint4*)&nmh[(size_t)v * DIM + c] = *(const uint4*)hi8;
    *(uint4*)&nml[(size_t)v * DIM + c] = *(const uint4*)lo8;
}

// ---------------------------------------------------------------------------
__global__ __launch_bounds__(256) void argmax_kernel(const float* __restrict__ logits,
                                                     float* __restrict__ out)
{
    const int row = blockIdx.x * 4 + (threadIdx.x >> 6);
    const int lane = threadIdx.x & 63;
    float bv = -1e30f; int bi = 1;
    for (int j = 1 + lane; j < N_OBJ_CLS; j += 64) {
        const float v = logits[(size_t)row * N_OBJ_CLS + j];
        if (v > bv) { bv = v; bi = j; }
    }
#pragma unroll
    for (int off = 32; off; off >>= 1) {
        const float ov = __shfl_xor(bv, off);
        const int oi = __shfl_xor(bi, off);
        if (ov > bv || (ov == bv && oi < bi)) { bv = ov; bi = oi; }
    }
    if (lane == 0) out[row] = (float)bi;
}

__global__ __launch_bounds__(256) void relinds_kernel(const int* __restrict__ rel,
                                                      float* __restrict__ out)
{
    const int i = blockIdx.x * 256 + threadIdx.x;
    out[i] = (float)rel[i];
}

// ---------------------------------------------------------------------------
extern "C" void kernel_launch(void* const* d_in, const int* in_sizes, int n_in,
                              void* d_out, int out_size, void* d_ws, size_t ws_size,
                              hipStream_t stream)
{
    const float* x_obj = (const float*)d_in[0];
    const float* x_pred = (const float*)d_in[1];
    const int* rel = (const int*)d_in[2];
    const float* oe_w1 = (const float*)d_in[3];
    const float* oe_b1 = (const float*)d_in[4];
    const float* oe_w2 = (const float*)d_in[5];
    const float* oe_b2 = (const float*)d_in[6];
    const float* pe_w1 = (const float*)d_in[7];
    const float* pe_b1 = (const float*)d_in[8];
    const float* pe_w2 = (const float*)d_in[9];
    const float* pe_b2 = (const float*)d_in[10];
    const float* g_sn_w = (const float*)d_in[11];
    const float* g_sn_b = (const float*)d_in[12];
    const float* g_on_w = (const float*)d_in[13];
    const float* g_on_b = (const float*)d_in[14];
    const float* g_se_w = (const float*)d_in[15];
    const float* g_se_b = (const float*)d_in[16];
    const float* g_oe_w = (const float*)d_in[17];
    const float* g_oe_b = (const float*)d_in[18];
    const float* ngru_wih = (const float*)d_in[19];
    const float* ngru_whh = (const float*)d_in[20];
    const float* ngru_bih = (const float*)d_in[21];
    const float* ngru_bhh = (const float*)d_in[22];
    const float* egru_wih = (const float*)d_in[23];
    const float* egru_whh = (const float*)d_in[24];
    const float* egru_bih = (const float*)d_in[25];
    const float* egru_bhh = (const float*)d_in[26];
    const float* op_w = (const float*)d_in[27];
    const float* op_b = (const float*)d_in[28];
    const float* pp_w = (const float*)d_in[29];
    const float* pp_b = (const float*)d_in[30];

    float* out = (float*)d_out;

    float* h_obj = out + OFF_HOBJ;       // f32 state written only at final step
    float* h_edge = out + OFF_HEDGE;

    // ---- workspace layout ----
    char* wsp = (char*)d_ws;
    float* af = (float*)wsp; wsp += N_RELS * 4;
    float* ag = (float*)wsp; wsp += N_RELS * 4;
    int* cs = (int*)wsp;   wsp += N_OBJS * 4;
    int* co = (int*)wsp;   wsp += N_OBJS * 4;
    int* offs = (int*)wsp; wsp += N_OBJS * 4;
    int* offo = (int*)wsp; wsp += N_OBJS * 4;
    int* curS = (int*)wsp; wsp += N_OBJS * 4;
    int* curO = (int*)wsp; wsp += N_OBJS * 4;
    int* listS = (int*)wsp; wsp += N_RELS * 4;
    int* listO = (int*)wsp; wsp += N_RELS * 4;

    u16* wp = (u16*)wsp;
    const int s_big = DIM * D_IN, s_sq = DIM * DIM, s_gru = 3 * DIM * DIM;
    // weights (f16)
    u16 *oe1h = wp; wp += s_big;
    u16 *pe1h = wp; wp += s_big;
    u16 *oe2h = wp; wp += s_sq;
    u16 *pe2h = wp; wp += s_sq;
    u16 *nih_h = wp; wp += s_gru;
    u16 *nhh_h = wp; wp += s_gru;
    u16 *eih_h = wp; wp += s_gru;
    u16 *ehh_h = wp; wp += s_gru;
    u16 *oph = wp; wp += 256 * DIM;
    u16 *pph = wp; wp += 128 * DIM;
    // f16 activations
    u16 *tmpo_h = wp; wp += (size_t)N_OBJS * DIM;   // enc1-obj out hi
    u16 *tmpo_l = wp; wp += (size_t)N_OBJS * DIM;   // enc1-obj out lo
    u16 *tmpe_h = wp; wp += (size_t)N_RELS * DIM;   // enc1-edge out (1-term)
    u16 *hhoh = wp; wp += (size_t)N_OBJS * DIM;     // h_obj shadow hi
    u16 *hhol = wp; wp += (size_t)N_OBJS * DIM;     // h_obj shadow lo
    u16 *hhe  = wp; wp += (size_t)N_RELS * DIM;     // h_edge shadow (1-term)
    u16 *emh  = wp; wp += (size_t)N_RELS * DIM;     // edge messages f16
    u16 *nmh  = wp; wp += (size_t)N_OBJS * DIM;     // node messages hi
    u16 *nml  = wp; wp += (size_t)N_OBJS * DIM;     // node messages lo
    // obj GRU gate buffers (separate from edge gi/gh to allow fused launch)
    u16 *gio = wp; wp += (size_t)N_OBJS * 1536;
    u16 *gho = wp; wp += (size_t)N_OBJS * 1536;

    // edge gi/gh chunk buffers (f16, R x 1536 each)
    const size_t used = (size_t)((char*)wp - (char*)d_ws);
    int R = 8192;
    if (used + (size_t)16384 * 6144 <= ws_size) R = 16384;
    u16* gi = wp;
    u16* gh = gi + (size_t)R * 1536;

    // all weight conversions in ONE launch
    convert_all<<<(CV_C9 + 255) / 256, 256, 0, stream>>>(
        oe_w1, oe1h, pe_w1, pe1h, oe_w2, oe2h, pe_w2, pe2h,
        ngru_wih, nih_h, ngru_whh, nhh_h, egru_wih, eih_h, egru_whh, ehh_h,
        op_w, oph, pp_w, pph);

    // CSR build
    hipMemsetAsync(cs, 0, 2 * N_OBJS * sizeof(int), stream);
    hipMemsetAsync(curS, 0, 2 * N_OBJS * sizeof(int), stream);
    count_int<<<N_RELS / 256, 256, 0, stream>>>(rel, cs, co);
    scan_off<<<1, 256, 0, stream>>>(cs, co, offs, offo);
    fill_csr<<<N_RELS / 256, 256, 0, stream>>>(rel, curS, curO, offs, offo, listS, listO);

    // enc1: FUSED edge(1-term) + obj(2-term split-out) in one launch
    enc1_both<<<1088, 256, 0, stream>>>(
        x_pred, pe1h, pe_b1, tmpe_h,
        x_obj, oe1h, oe_b1, tmpo_h, tmpo_l);
    // enc2: separate (preserves edge AT1 occupancy)
    gemm_f16<1, false, true, false><<<4 * (N_RELS / 128), 256, 0, stream>>>(
        tmpe_h, nullptr, pe2h, pe_b2, nullptr, hhe, nullptr, 4, DIM, DIM, DIM);
    gemm_f16<2, false, true, true><<<4 * (N_OBJS / 128), 256, 0, stream>>>(
        tmpo_h, tmpo_l, oe2h, oe_b2, nullptr, hhoh, hhol, 4, DIM, DIM, DIM);

    // message-passing steps (f16 state between steps; f32 out at last step)
    for (int step = 0; step < 2; step++) {
        gatepass<<<N_RELS / 4, 256, 0, stream>>>(
            hhoh, hhe, rel,
            g_sn_w, g_sn_b, g_on_w, g_on_b, g_se_w, g_se_b, g_oe_w, g_oe_b,
            cs, co, emh, af, ag);
        gather_nm<<<N_OBJS / 4, 256, 0, stream>>>(
            hhe, listS, listO, offs, offo, cs, co, af, ag, nmh, nml);

        // chunk 0: FUSED edge GRU (rows [0,Rc0)) + obj GRU (384 AT2 blocks)
        const int Rc0 = (N_RELS < R) ? N_RELS : R;
        const int nEdge = 24 * (Rc0 / 128);
        gru_edge_obj<<<nEdge + 24 * (N_OBJS / 128), 256, 0, stream>>>(
            emh, eih_h, egru_bih, gi, hhe, ehh_h, egru_bhh, gh, nEdge,
            nmh, nml, nih_h, ngru_bih, gio,
            hhoh, hhol, nhh_h, ngru_bhh, gho);

        // obj combine
        if (step == 0)
            gru_combine<true, false><<<(N_OBJS * 128 + 255) / 256, 256, 0, stream>>>(
                gio, gho, hhoh, hhol, nullptr, N_OBJS);
        else
            gru_combine<true, true><<<(N_OBJS * 128 + 255) / 256, 256, 0, stream>>>(
                gio, gho, hhoh, hhol, h_obj, N_OBJS);
        // edge combine chunk 0
        if (step == 0)
            gru_combine<false, false><<<(Rc0 * 128 + 255) / 256, 256, 0, stream>>>(
                gi, gh, hhe, nullptr, nullptr, Rc0);
        else
            gru_combine<false, true><<<(Rc0 * 128 + 255) / 256, 256, 0, stream>>>(
                gi, gh, hhe, nullptr, h_edge, Rc0);

        // remaining edge chunks (plain 32KB kernel)
        for (int r0 = Rc0; r0 < N_RELS; r0 += R) {
            const int Rc = (N_RELS - r0 < R) ? (N_RELS - r0) : R;
            gru_gemm_e<<<24 * (Rc / 128), 256, 0, stream>>>(
                emh + (size_t)r0 * DIM, eih_h, egru_bih, gi,
                hhe + (size_t)r0 * DIM, ehh_h, egru_bhh, gh);
            if (step == 0)
                gru_combine<false, false><<<(Rc * 128 + 255) / 256, 256, 0, stream>>>(
                    gi, gh, hhe + (size_t)r0 * DIM, nullptr, nullptr, Rc);
            else
                gru_combine<false, true><<<(Rc * 128 + 255) / 256, 256, 0, stream>>>(
                    gi, gh, hhe + (size_t)r0 * DIM, nullptr, h_edge + (size_t)r0 * DIM, Rc);
        }
    }

    // classifiers: FUSED edge(1-term) + obj(2-term, labels) in one launch
    cls_both<<<288, 256, 0, stream>>>(
        hhe, pph, pp_b, out + OFF_PLOG,
        hhoh, hhol, oph, op_b, out + OFF_OLOG);

    // labels + rel_inds passthrough
    argmax_kernel<<<N_OBJS / 4, 256, 0, stream>>>(out + OFF_OLOG, out + OFF_LBL);
    relinds_kernel<<<(2 * N_RELS) / 256, 256, 0, stream>>>(rel, out + OFF_RI);
}

// Round 19
// 982.267 us; speedup vs baseline: 1.0498x; 1.0498x over previous
//
#include <hip/hip_runtime.h>
#include <math.h>

typedef unsigned short u16;
typedef unsigned int u32;
typedef _Float16 f16;
typedef f16 f16x8 __attribute__((ext_vector_type(8)));
typedef float f32x4 __attribute__((ext_vector_type(4)));

#define DIM 512
#define D_IN 4096
#define N_OBJS 2048
#define N_RELS 32768
#define N_OBJ_CLS 151
#define N_REL_CLS 51
#define EPSV 1e-5f

// d_out layout (floats)
#define OFF_HOBJ  0
#define OFF_HEDGE (N_OBJS*DIM)
#define OFF_OLOG  (OFF_HEDGE + N_RELS*DIM)
#define OFF_PLOG  (OFF_OLOG + N_OBJS*N_OBJ_CLS)
#define OFF_LBL   (OFF_PLOG + N_RELS*N_REL_CLS)
#define OFF_RI    (OFF_LBL + N_OBJS)

__device__ __forceinline__ float sigmoidf_(float x) { return 1.0f / (1.0f + expf(-x)); }
__device__ __forceinline__ u16 f2h_(float f) {
    union { f16 h; u16 u; } c; c.h = (f16)f; return c.u;
}
__device__ __forceinline__ float h2f_(u16 u) {
    union { f16 h; u16 u; } c; c.u = u; return (float)c.h;
}

// 8 fp32 -> packed f16 (uint4)
__device__ __forceinline__ void cvt8h1(const float* f, uint4& h) {
    u32 hh[8];
#pragma unroll
    for (int i = 0; i < 8; i++) hh[i] = f2h_(f[i]);
    h.x = hh[0] | (hh[1] << 16); h.y = hh[2] | (hh[3] << 16);
    h.z = hh[4] | (hh[5] << 16); h.w = hh[6] | (hh[7] << 16);
}
// 8 fp32 -> hi + lo (a ~= hi + lo)
__device__ __forceinline__ void cvt8h2(const float* f, uint4& h, uint4& l) {
    u32 hh[8], ll[8];
#pragma unroll
    for (int i = 0; i < 8; i++) {
        u16 x = f2h_(f[i]);
        hh[i] = x;
        ll[i] = f2h_(f[i] - h2f_(x));
    }
    h.x = hh[0] | (hh[1] << 16); h.y = hh[2] | (hh[3] << 16);
    h.z = hh[4] | (hh[5] << 16); h.w = hh[6] | (hh[7] << 16);
    l.x = ll[0] | (ll[1] << 16); l.y = ll[2] | (ll[3] << 16);
    l.z = ll[4] | (ll[5] << 16); l.w = ll[6] | (ll[7] << 16);
}

// LDS offset (u16 units) for (row, chunk8) in a [rows][32] tile, XOR-swizzled
__device__ __forceinline__ int swzo(int row, int c) {
    return row * 32 + ((c ^ ((row >> 1) & 3)) << 3);
}

// XCD-chunked bijective blockIdx swizzle (requires nwg % 8 == 0)
__device__ __forceinline__ int xcdswz(int orig, int nwg) {
    const int q = nwg >> 3;
    return (orig & 7) * q + (orig >> 3);
}

// async global->LDS, 16B per lane; LDS dest = wave-uniform base + lane*16
__device__ __forceinline__ void gload16(const void* g, void* l) {
    __builtin_amdgcn_global_load_lds(
        (const __attribute__((address_space(1))) void*)g,
        (__attribute__((address_space(3))) void*)l, 16, 0, 0);
}

// ---------------------------------------------------------------------------
// ONE-SHOT weight conversion: all 10 fp32 weight tensors -> f16 in a single
// launch. Segment boundaries are compile-time constants (quad = ushort4 units).
// ---------------------------------------------------------------------------
#define Q_BIG  (DIM * D_IN / 4)
#define Q_SQ   (DIM * DIM / 4)
#define Q_GRU  (3 * DIM * DIM / 4)
#define Q_OP   (N_OBJ_CLS * DIM / 4)
#define Q_PP   (N_REL_CLS * DIM / 4)
#define CV_C0  (Q_BIG)
#define CV_C1  (CV_C0 + Q_BIG)
#define CV_C2  (CV_C1 + Q_SQ)
#define CV_C3  (CV_C2 + Q_SQ)
#define CV_C4  (CV_C3 + Q_GRU)
#define CV_C5  (CV_C4 + Q_GRU)
#define CV_C6  (CV_C5 + Q_GRU)
#define CV_C7  (CV_C6 + Q_GRU)
#define CV_C8  (CV_C7 + Q_OP)
#define CV_C9  (CV_C8 + Q_PP)

__global__ __launch_bounds__(256) void convert_all(
    const float* __restrict__ s0, u16* __restrict__ d0,
    const float* __restrict__ s1, u16* __restrict__ d1,
    const float* __restrict__ s2, u16* __restrict__ d2,
    const float* __restrict__ s3, u16* __restrict__ d3,
    const float* __restrict__ s4, u16* __restrict__ d4,
    const float* __restrict__ s5, u16* __restrict__ d5,
    const float* __restrict__ s6, u16* __restrict__ d6,
    const float* __restrict__ s7, u16* __restrict__ d7,
    const float* __restrict__ s8, u16* __restrict__ d8,
    const float* __restrict__ s9, u16* __restrict__ d9)
{
    int i = blockIdx.x * 256 + threadIdx.x;
    if (i >= CV_C9) return;
    const float* src; u16* dst; int base;
    if      (i < CV_C0) { src = s0; dst = d0; base = 0; }
    else if (i < CV_C1) { src = s1; dst = d1; base = CV_C0; }
    else if (i < CV_C2) { src = s2; dst = d2; base = CV_C1; }
    else if (i < CV_C3) { src = s3; dst = d3; base = CV_C2; }
    else if (i < CV_C4) { src = s4; dst = d4; base = CV_C3; }
    else if (i < CV_C5) { src = s5; dst = d5; base = CV_C4; }
    else if (i < CV_C6) { src = s6; dst = d6; base = CV_C5; }
    else if (i < CV_C7) { src = s7; dst = d7; base = CV_C6; }
    else if (i < CV_C8) { src = s8; dst = d8; base = CV_C7; }
    else                { src = s9; dst = d9; base = CV_C8; }
    const int q = i - base;
    const float4 v = ((const float4*)src)[q];
    ((ushort4*)dst)[q] = make_ushort4(f2h_(v.x), f2h_(v.y), f2h_(v.z), f2h_(v.w));
}

// ---------------------------------------------------------------------------
// BODY: f16 GEMM, fp32 A split on the fly (AT terms), 1-deep A-reg prefetch,
// B f16 via global_load_lds. Caller provides LDS. BK=32, N = NX*128 exact.
// ---------------------------------------------------------------------------
template<bool RELU, int AT, bool WSPLIT>
__device__ __forceinline__ void gemm_a32_body(
    int id, u16* sAh, u16* sBh, u16* sAl,
    const float* __restrict__ A, const u16* __restrict__ Bhi,
    const float* __restrict__ bias, u16* __restrict__ Chi, u16* __restrict__ Clo,
    int NX, int K)
{
    const int m0 = (id / NX) * 128, n0 = (id % NX) * 128;
    const int N = NX * 128;
    const int t = threadIdx.x;
    const int wid = t >> 6, lane = t & 63;
    const int wm = (wid >> 1) * 64, wn = (wid & 1) * 64;
    const int lr = lane & 15, lk = lane >> 4;

    f32x4 acc[4][4] = {};

    const int sr = t >> 1;
    const int sc = (t & 1) * 2;
    const float* Ap = A + (size_t)(m0 + sr) * K + (t & 1) * 16;

    const int rB = (wid * 2) * 16 + (lane >> 2);
    const int cB = (lane & 3) ^ ((rB >> 1) & 3);
    const u16* Bp0 = Bhi + (size_t)(n0 + rB) * K + cB * 8;
    const u16* Bp1 = Bp0 + (size_t)16 * K;
    u16* Bd0 = &sBh[(wid * 2) * 512];
    u16* Bd1 = Bd0 + 512;

    float fv[16];
    *(float4*)&fv[0]  = *(const float4*)(Ap);
    *(float4*)&fv[4]  = *(const float4*)(Ap + 4);
    *(float4*)&fv[8]  = *(const float4*)(Ap + 8);
    *(float4*)&fv[12] = *(const float4*)(Ap + 12);

    for (int k0 = 0; k0 < K; k0 += 32) {
        uint4 ah0, ah1, al0, al1;
        if (AT == 2) { cvt8h2(fv, ah0, al0); cvt8h2(fv + 8, ah1, al1); }
        else         { cvt8h1(fv, ah0);      cvt8h1(fv + 8, ah1); }

        __syncthreads();                       // previous LDS reads complete
        gload16(Bp0 + k0, Bd0);
        gload16(Bp1 + k0, Bd1);
        *(uint4*)&sAh[swzo(sr, sc)]     = ah0;
        *(uint4*)&sAh[swzo(sr, sc + 1)] = ah1;
        if (AT == 2) {
            *(uint4*)&sAl[swzo(sr, sc)]     = al0;
            *(uint4*)&sAl[swzo(sr, sc + 1)] = al1;
        }
        asm volatile("s_waitcnt vmcnt(0)" ::: "memory");
        __syncthreads();

        const int kn = k0 + 32;
        if (kn < K) {
            *(float4*)&fv[0]  = *(const float4*)(Ap + kn);
            *(float4*)&fv[4]  = *(const float4*)(Ap + kn + 4);
            *(float4*)&fv[8]  = *(const float4*)(Ap + kn + 8);
            *(float4*)&fv[12] = *(const float4*)(Ap + kn + 12);
        }

        f16x8 ah[4], al[4], bh[4];
#pragma unroll
        for (int f = 0; f < 4; f++) {
            const int off = swzo(wm + f * 16 + lr, lk);
            ah[f] = *(const f16x8*)&sAh[off];
            if (AT == 2) al[f] = *(const f16x8*)&sAl[off];
            bh[f] = *(const f16x8*)&sBh[swzo(wn + f * 16 + lr, lk)];
        }
#pragma unroll
        for (int fm = 0; fm < 4; fm++)
#pragma unroll
            for (int fn = 0; fn < 4; fn++) {
                acc[fm][fn] = __builtin_amdgcn_mfma_f32_16x16x32_f16(ah[fm], bh[fn], acc[fm][fn], 0, 0, 0);
                if (AT == 2)
                    acc[fm][fn] = __builtin_amdgcn_mfma_f32_16x16x32_f16(al[fm], bh[fn], acc[fm][fn], 0, 0, 0);
            }
    }
#pragma unroll
    for (int fm = 0; fm < 4; fm++) {
        const int mrow = m0 + wm + fm * 16 + lk * 4;
#pragma unroll
        for (int fn = 0; fn < 4; fn++) {
            const int col = n0 + wn + fn * 16 + lr;
            const float bv = bias[col];
#pragma unroll
            for (int j = 0; j < 4; j++) {
                float v = acc[fm][fn][j] + bv;
                if (RELU) v = fmaxf(v, 0.0f);
                const u16 h = f2h_(v);
                Chi[(size_t)(mrow + j) * N + col] = h;
                if (WSPLIT) Clo[(size_t)(mrow + j) * N + col] = f2h_(v - h2f_(h));
            }
        }
    }
}

// FUSED enc1: ids [0,1024) = edge (AT1), ids [1024,1088) = obj (AT2, split out)
__global__ __launch_bounds__(256, 3) void enc1_both(
    const float* __restrict__ xp, const u16* __restrict__ pw,
    const float* __restrict__ pb, u16* __restrict__ tmpe,
    const float* __restrict__ xo, const u16* __restrict__ ow,
    const float* __restrict__ ob, u16* __restrict__ tmpoh, u16* __restrict__ tmpol)
{
    __shared__ u16 smem[3 * 4096];
    const int id = xcdswz(blockIdx.x, gridDim.x);
    if (id < 1024)
        gemm_a32_body<true, 1, false>(id, smem, smem + 4096, nullptr,
                                      xp, pw, pb, tmpe, nullptr, 4, D_IN);
    else
        gemm_a32_body<true, 2, true>(id - 1024, smem, smem + 4096, smem + 8192,
                                     xo, ow, ob, tmpoh, tmpol, 4, D_IN);
}

// ---------------------------------------------------------------------------
// BODY: f16 GEMM, A presplit (hi [+lo if AT=2]), B f16; all via gload_lds.
// BK=64. LDS: sA0=0, sA1=4096, sB0=8192, sB1=12288, [sL0=16384, sL1=20480].
// ---------------------------------------------------------------------------
template<int AT, bool WF32, bool WHI, bool WLO>
__device__ __forceinline__ void gemm_f16_body(
    int id, u16* smem,
    const u16* __restrict__ Ahi, const u16* __restrict__ Alo,
    const u16* __restrict__ Bhi, const float* __restrict__ bias,
    float* __restrict__ C32, u16* __restrict__ Chi, u16* __restrict__ Clo,
    int NX, int N, int ldc, int K)
{
    const int m0 = (id / NX) * 128, n0 = (id % NX) * 128;
    const int t = threadIdx.x;
    const int wid = t >> 6, lane = t & 63;
    const int wm = (wid >> 1) * 64, wn = (wid & 1) * 64;
    const int lr = lane & 15, lk = lane >> 4;

    f32x4 acc[4][4] = {};

    const int rr = (wid * 2) * 16 + (lane >> 2);
    const int cc = (lane & 3) ^ ((rr >> 1) & 3);
    const u16* pA0 = Ahi + (size_t)(m0 + rr) * K + cc * 8;
    const u16* pA1 = pA0 + (size_t)16 * K;
    const u16* pL0 = (AT == 2) ? Alo + (size_t)(m0 + rr) * K + cc * 8 : nullptr;
    const u16* pL1 = (AT == 2) ? pL0 + (size_t)16 * K : nullptr;
    const u16* pB0 = Bhi + (size_t)(n0 + rr) * K + cc * 8;
    const u16* pB1 = pB0 + (size_t)16 * K;
    const int bOff = (wid * 2) * 512;

    for (int k0 = 0; k0 < K; k0 += 64) {
        __syncthreads();
#pragma unroll
        for (int h = 0; h < 2; h++) {
            const int kk = k0 + h * 32;
            u16* sA_ = smem + h * 4096;
            u16* sB_ = smem + 8192 + h * 4096;
            gload16(pA0 + kk, sA_ + bOff);
            gload16(pA1 + kk, sA_ + bOff + 512);
            if (AT == 2) {
                u16* sL_ = smem + 16384 + h * 4096;
                gload16(pL0 + kk, sL_ + bOff);
                gload16(pL1 + kk, sL_ + bOff + 512);
            }
            gload16(pB0 + kk, sB_ + bOff);
            gload16(pB1 + kk, sB_ + bOff + 512);
        }
        asm volatile("s_waitcnt vmcnt(0)" ::: "memory");
        __syncthreads();

#pragma unroll
        for (int h = 0; h < 2; h++) {
            const u16* sA_ = smem + h * 4096;
            const u16* sB_ = smem + 8192 + h * 4096;
            const u16* sL_ = smem + 16384 + h * 4096;
            f16x8 ah[4], al[4], bh[4];
#pragma unroll
            for (int f = 0; f < 4; f++) {
                const int off = swzo(wm + f * 16 + lr, lk);
                ah[f] = *(const f16x8*)&sA_[off];
                if (AT == 2) al[f] = *(const f16x8*)&sL_[off];
                bh[f] = *(const f16x8*)&sB_[swzo(wn + f * 16 + lr, lk)];
            }
#pragma unroll
            for (int fm = 0; fm < 4; fm++)
#pragma unroll
                for (int fn = 0; fn < 4; fn++) {
                    acc[fm][fn] = __builtin_amdgcn_mfma_f32_16x16x32_f16(ah[fm], bh[fn], acc[fm][fn], 0, 0, 0);
                    if (AT == 2)
                        acc[fm][fn] = __builtin_amdgcn_mfma_f32_16x16x32_f16(al[fm], bh[fn], acc[fm][fn], 0, 0, 0);
                }
        }
    }
#pragma unroll
    for (int fm = 0; fm < 4; fm++) {
        const int mrow = m0 + wm + fm * 16 + lk * 4;
#pragma unroll
        for (int fn = 0; fn < 4; fn++) {
            const int col = n0 + wn + fn * 16 + lr;
            const float bv = bias[col];
#pragma unroll
            for (int j = 0; j < 4; j++) {
                const float v = acc[fm][fn][j] + bv;
                if (WF32 && col < N) C32[(size_t)(mrow + j) * ldc + col] = v;
                if (WHI) {
                    const u16 h = f2h_(v);
                    Chi[(size_t)(mrow + j) * (NX * 128) + col] = h;
                    if (WLO)
                        Clo[(size_t)(mrow + j) * (NX * 128) + col] = f2h_(v - h2f_(h));
                }
            }
        }
    }
}

// Standalone presplit GEMM kernels (enc2)
template<int AT, bool WF32, bool WHI, bool WLO>
__global__ __launch_bounds__(256, AT == 1 ? 4 : 3) void gemm_f16(
    const u16* __restrict__ Ahi, const u16* __restrict__ Alo,
    const u16* __restrict__ Bhi, const float* __restrict__ bias,
    float* __restrict__ C32, u16* __restrict__ Chi, u16* __restrict__ Clo,
    int NX, int N, int ldc, int K)
{
    __shared__ u16 smem[AT == 2 ? 6 * 4096 : 4 * 4096];
    const int id = xcdswz(blockIdx.x, gridDim.x);
    gemm_f16_body<AT, WF32, WHI, WLO>(id, smem, Ahi, Alo, Bhi, bias,
                                      C32, Chi, Clo, NX, N, ldc, K);
}

// FUSED classifiers: ids [0,256) = edge cls (AT1), [256,288) = obj cls (AT2)
__global__ __launch_bounds__(256, 3) void cls_both(
    const u16* __restrict__ hhe, const u16* __restrict__ pph,
    const float* __restrict__ ppb, float* __restrict__ plog,
    const u16* __restrict__ hhoh, const u16* __restrict__ hhol,
    const u16* __restrict__ oph, const float* __restrict__ opb,
    float* __restrict__ olog)
{
    __shared__ u16 smem[6 * 4096];
    const int id = xcdswz(blockIdx.x, gridDim.x);
    if (id < 256)
        gemm_f16_body<1, true, false, false>(id, smem, hhe, nullptr, pph, ppb,
                                             plog, nullptr, nullptr,
                                             1, N_REL_CLS, N_REL_CLS, DIM);
    else
        gemm_f16_body<2, true, false, false>(id - 256, smem, hhoh, hhol, oph, opb,
                                             olog, nullptr, nullptr,
                                             2, N_OBJ_CLS, N_OBJ_CLS, DIM);
}

// ---------------------------------------------------------------------------
// Merged GRU GEMM: part<12 -> gi = X@Wih^T+bih; part>=12 -> gh = H@Whh^T+bhh.
// A presplit (AT terms), BK=64, f16 out ldc=1536. 1D grid, XCD-swizzled.
// ---------------------------------------------------------------------------
template<int AT>
__global__ __launch_bounds__(256, AT == 1 ? 4 : 3) void gru_gemm2(
    const u16* __restrict__ Xh, const u16* __restrict__ Xl,
    const u16* __restrict__ WiH, const float* __restrict__ bi, u16* __restrict__ gi,
    const u16* __restrict__ Hh, const u16* __restrict__ Hl,
    const u16* __restrict__ WhH, const float* __restrict__ bhs, u16* __restrict__ gh_,
    int K)
{
    __shared__ u16 smem[AT == 2 ? 6 * 4096 : 4 * 4096];
    const int id = xcdswz(blockIdx.x, gridDim.x);
    const int part = id % 24;
    const int m0b = id / 24;
    const bool isH = part >= 12;
    const u16* Ahi = isH ? Hh : Xh;
    const u16* Alo = isH ? Hl : Xl;
    const u16* Bhi = isH ? WhH : WiH;
    const float* bias = isH ? bhs : bi;
    u16* C = isH ? gh_ : gi;
    const int nblk = part - (isH ? 12 : 0);
    gemm_f16_body<AT, false, true, false>(m0b * 12 + nblk, smem,
                                          Ahi, Alo, Bhi, bias,
                                          nullptr, C, nullptr, 12, 1536, 1536, K);
}

// ---------------------------------------------------------------------------
// GRU combine: gi/gh f16 [R x 1536]; old h read from f16 shadow (hi [+lo]);
// writes shadow (hi [+lo]) and optionally the final f32 state.
// ---------------------------------------------------------------------------
__device__ __forceinline__ float gcomb(u16 ir, u16 iz, u16 in_, u16 hr, u16 hz,
                                       u16 hn, float h) {
    const float r = sigmoidf_(h2f_(ir) + h2f_(hr));
    const float z = sigmoidf_(h2f_(iz) + h2f_(hz));
    const float n = tanhf(h2f_(in_) + r * h2f_(hn));
    return (1.0f - z) * n + z * h;
}

template<bool WSPLIT, bool WF32>
__global__ __launch_bounds__(256) void gru_combine(
    const u16* __restrict__ gi, const u16* __restrict__ gh,
    u16* __restrict__ hh, u16* __restrict__ hl, float* __restrict__ H32, int R)
{
    const int idx = blockIdx.x * 256 + threadIdx.x;      // R*128 quads
    if (idx >= R * 128) return;
    const int r = idx >> 7, c4 = (idx & 127) * 4;
    const size_t gb = (size_t)r * 1536 + c4;
    const ushort4 ir4 = *(const ushort4*)&gi[gb];
    const ushort4 iz4 = *(const ushort4*)&gi[gb + 512];
    const ushort4 in4 = *(const ushort4*)&gi[gb + 1024];
    const ushort4 hr4 = *(const ushort4*)&gh[gb];
    const ushort4 hz4 = *(const ushort4*)&gh[gb + 512];
    const ushort4 hn4 = *(const ushort4*)&gh[gb + 1024];
    const size_t hb = (size_t)r * 512 + c4;
    const ushort4 hhi = *(const ushort4*)&hh[hb];
    float h0 = h2f_(hhi.x), h1 = h2f_(hhi.y), h2 = h2f_(hhi.z), h3 = h2f_(hhi.w);
    if (WSPLIT) {
        const ushort4 hlo = *(const ushort4*)&hl[hb];
        h0 += h2f_(hlo.x); h1 += h2f_(hlo.y); h2 += h2f_(hlo.z); h3 += h2f_(hlo.w);
    }
    float4 o;
    o.x = gcomb(ir4.x, iz4.x, in4.x, hr4.x, hz4.x, hn4.x, h0);
    o.y = gcomb(ir4.y, iz4.y, in4.y, hr4.y, hz4.y, hn4.y, h1);
    o.z = gcomb(ir4.z, iz4.z, in4.z, hr4.z, hz4.z, hn4.z, h2);
    o.w = gcomb(ir4.w, iz4.w, in4.w, hr4.w, hz4.w, hn4.w, h3);
    const ushort4 hi4 = make_ushort4(f2h_(o.x), f2h_(o.y), f2h_(o.z), f2h_(o.w));
    *(ushort4*)&hh[hb] = hi4;
    if (WSPLIT) {
        *(ushort4*)&hl[hb] = make_ushort4(
            f2h_(o.x - h2f_(hi4.x)), f2h_(o.y - h2f_(hi4.y)),
            f2h_(o.z - h2f_(hi4.z)), f2h_(o.w - h2f_(hi4.w)));
    }
    if (WF32) *(float4*)&H32[hb] = o;
}

// ---------------------------------------------------------------------------
// CSR build
// ---------------------------------------------------------------------------
__global__ __launch_bounds__(256) void count_int(const int* __restrict__ rel,
                                                 int* cs, int* co)
{
    const int e = blockIdx.x * 256 + threadIdx.x;
    atomicAdd(&cs[rel[2 * e]], 1);
    atomicAdd(&co[rel[2 * e + 1]], 1);
}

__global__ __launch_bounds__(256) void scan_off(const int* __restrict__ cs,
    const int* __restrict__ co, int* __restrict__ offs, int* __restrict__ offo)
{
    __shared__ int tmp[256];
    for (int arr = 0; arr < 2; arr++) {
        const int* c = arr ? co : cs;
        int* off = arr ? offo : offs;
        const int base = threadIdx.x * 8;
        int loc[8]; int s = 0;
#pragma unroll
        for (int j = 0; j < 8; j++) { loc[j] = c[base + j]; s += loc[j]; }
        tmp[threadIdx.x] = s;
        __syncthreads();
        for (int d = 1; d < 256; d <<= 1) {
            const int v = (threadIdx.x >= d) ? tmp[threadIdx.x - d] : 0;
            __syncthreads();
            tmp[threadIdx.x] += v;
            __syncthreads();
        }
        int p = tmp[threadIdx.x] - s;    // exclusive prefix
#pragma unroll
        for (int j = 0; j < 8; j++) { off[base + j] = p; p += loc[j]; }
        __syncthreads();
    }
}

// fill CSR lists + write rel_inds passthrough (float) in the same pass
__global__ __launch_bounds__(256) void fill_csr(const int* __restrict__ rel,
    int* curS, int* curO, const int* __restrict__ offs, const int* __restrict__ offo,
    int* __restrict__ listS, int* __restrict__ listO, float* __restrict__ outri)
{
    const int e = blockIdx.x * 256 + threadIdx.x;
    const int s = rel[2 * e], o = rel[2 * e + 1];
    const int i = atomicAdd(&curS[s], 1);
    listS[offs[s] + i] = e;
    const int j = atomicAdd(&curO[o], 1);
    listO[offo[o] + j] = e;
    outri[2 * e]     = (float)s;
    outri[2 * e + 1] = (float)o;
}

// ---------------------------------------------------------------------------
// Gates + edge messages, one WAVE per edge (no barrier, no atomics).
// ---------------------------------------------------------------------------
__global__ __launch_bounds__(256) void gatepass(
    const u16* __restrict__ hho, const u16* __restrict__ hhe,
    const int* __restrict__ rel,
    const float* __restrict__ wsn, const float* __restrict__ bsn,
    const float* __restrict__ won, const float* __restrict__ bon,
    const float* __restrict__ wse, const float* __restrict__ bse,
    const float* __restrict__ woe, const float* __restrict__ boe,
    const int* __restrict__ cs, const int* __restrict__ co,
    u16* __restrict__ emh, float* __restrict__ af, float* __restrict__ ag)
{
    const int e = blockIdx.x * 4 + (threadIdx.x >> 6);
    const int lane = threadIdx.x & 63;
    const int s = rel[2 * e], o = rel[2 * e + 1];
    const int c = lane * 8;

    const uint4 hsu = *(const uint4*)&hho[(size_t)s * DIM + c];
    const uint4 hou = *(const uint4*)&hho[(size_t)o * DIM + c];
    const uint4 heu = *(const uint4*)&hhe[(size_t)e * DIM + c];
    float hs[8], ho[8], he[8];
    hs[0] = h2f_((u16)hsu.x); hs[1] = h2f_((u16)(hsu.x >> 16));
    hs[2] = h2f_((u16)hsu.y); hs[3] = h2f_((u16)(hsu.y >> 16));
    hs[4] = h2f_((u16)hsu.z); hs[5] = h2f_((u16)(hsu.z >> 16));
    hs[6] = h2f_((u16)hsu.w); hs[7] = h2f_((u16)(hsu.w >> 16));
    ho[0] = h2f_((u16)hou.x); ho[1] = h2f_((u16)(hou.x >> 16));
    ho[2] = h2f_((u16)hou.y); ho[3] = h2f_((u16)(hou.y >> 16));
    ho[4] = h2f_((u16)hou.z); ho[5] = h2f_((u16)(hou.z >> 16));
    ho[6] = h2f_((u16)hou.w); ho[7] = h2f_((u16)(hou.w >> 16));
    he[0] = h2f_((u16)heu.x); he[1] = h2f_((u16)(heu.x >> 16));
    he[2] = h2f_((u16)heu.y); he[3] = h2f_((u16)(heu.y >> 16));
    he[4] = h2f_((u16)heu.z); he[5] = h2f_((u16)(heu.z >> 16));
    he[6] = h2f_((u16)heu.w); he[7] = h2f_((u16)(heu.w >> 16));

    float p0 = 0.f, p1 = 0.f, p2 = 0.f, p3 = 0.f;
#pragma unroll
    for (int q = 0; q < 2; q++) {
        const float4 w0v = *(const float4*)&wsn[c + q * 4];
        const float4 w0e = *(const float4*)&wsn[DIM + c + q * 4];
        const float4 w1v = *(const float4*)&won[c + q * 4];
        const float4 w1e = *(const float4*)&won[DIM + c + q * 4];
        const float4 w2v = *(const float4*)&wse[c + q * 4];
        const float4 w2e = *(const float4*)&wse[DIM + c + q * 4];
        const float4 w3v = *(const float4*)&woe[c + q * 4];
        const float4 w3e = *(const float4*)&woe[DIM + c + q * 4];
        const float* s4 = &hs[q * 4];
        const float* o4 = &ho[q * 4];
        const float* e4 = &he[q * 4];
        p0 += s4[0]*w0v.x + s4[1]*w0v.y + s4[2]*w0v.z + s4[3]*w0v.w
            + e4[0]*w0e.x + e4[1]*w0e.y + e4[2]*w0e.z + e4[3]*w0e.w;
        p1 += o4[0]*w1v.x + o4[1]*w1v.y + o4[2]*w1v.z + o4[3]*w1v.w
            + e4[0]*w1e.x + e4[1]*w1e.y + e4[2]*w1e.z + e4[3]*w1e.w;
        p2 += s4[0]*w2v.x + s4[1]*w2v.y + s4[2]*w2v.z + s4[3]*w2v.w
            + e4[0]*w2e.x + e4[1]*w2e.y + e4[2]*w2e.z + e4[3]*w2e.w;
        p3 += o4[0]*w3v.x + o4[1]*w3v.y + o4[2]*w3v.z + o4[3]*w3v.w
            + e4[0]*w3e.x + e4[1]*w3e.y + e4[2]*w3e.z + e4[3]*w3e.w;
    }
#pragma unroll
    for (int off = 32; off; off >>= 1) {
        p0 += __shfl_xor(p0, off);
        p1 += __shfl_xor(p1, off);
        p2 += __shfl_xor(p2, off);
        p3 += __shfl_xor(p3, off);
    }
    const float gsn = sigmoidf_(p0 + bsn[0]);
    const float gon = sigmoidf_(p1 + bon[0]);
    const float gse = sigmoidf_(p2 + bse[0]);
    const float goe = sigmoidf_(p3 + boe[0]);

    if (lane == 0) {
        af[e] = 0.5f * gsn / ((float)cs[s] + EPSV);
        ag[e] = 0.5f * gon / ((float)co[o] + EPSV);
    }
    u16 em8[8];
#pragma unroll
    for (int j = 0; j < 8; j++)
        em8[j] = f2h_(0.5f * (gse * hs[j] + goe * ho[j]));
    *(uint4*)&emh[(size_t)e * DIM + c] = *(const uint4*)em8;
}

// ---------------------------------------------------------------------------
// Node-message gather (no atomics), reading f16 h_edge shadow.
// ---------------------------------------------------------------------------
__global__ __launch_bounds__(256) void gather_nm(
    const u16* __restrict__ hhe,
    const int* __restrict__ listS, const int* __restrict__ listO,
    const int* __restrict__ offs, const int* __restrict__ offo,
    const int* __restrict__ cs, const int* __restrict__ co,
    const float* __restrict__ af, const float* __restrict__ ag,
    u16* __restrict__ nmh, u16* __restrict__ nml)
{
    const int v = blockIdx.x * 4 + (threadIdx.x >> 6);
    const int lane = threadIdx.x & 63;
    const int c = lane * 8;

    float acc[8] = {};
#pragma unroll
    for (int side = 0; side < 2; side++) {
        const int* list = side ? listO : listS;
        const int b = side ? offo[v] : offs[v];
        const int n = side ? co[v] : cs[v];
        const float* coef = side ? ag : af;
        for (int i = 0; i < n; i++) {
            const int e = list[b + i];
            const float a = coef[e];
            const uint4 x = *(const uint4*)&hhe[(size_t)e * DIM + c];
            acc[0] += a * h2f_((u16)x.x); acc[1] += a * h2f_((u16)(x.x >> 16));
            acc[2] += a * h2f_((u16)x.y); acc[3] += a * h2f_((u16)(x.y >> 16));
            acc[4] += a * h2f_((u16)x.z); acc[5] += a * h2f_((u16)(x.z >> 16));
            acc[6] += a * h2f_((u16)x.w); acc[7] += a * h2f_((u16)(x.w >> 16));
        }
    }
    u16 hi8[8], lo8[8];
#pragma unroll
    for (int j = 0; j < 8; j++) {
        hi8[j] = f2h_(acc[j]);
        lo8[j] = f2h_(acc[j] - h2f_(hi8[j]));
    }
    *(uint4*)&nmh[(size_t)v * DIM + c] = *(const uint4*)hi8;
    *(uint4*)&nml[(size_t)v * DIM + c] = *(const uint4*)lo8;
}

// ---------------------------------------------------------------------------
__global__ __launch_bounds__(256) void argmax_kernel(const float* __restrict__ logits,
                                                     float* __restrict__ out)
{
    const int row = blockIdx.x * 4 + (threadIdx.x >> 6);
    const int lane = threadIdx.x & 63;
    float bv = -1e30f; int bi = 1;
    for (int j = 1 + lane; j < N_OBJ_CLS; j += 64) {
        const float v = logits[(size_t)row * N_OBJ_CLS + j];
        if (v > bv) { bv = v; bi = j; }
    }
#pragma unroll
    for (int off = 32; off; off >>= 1) {
        const float ov = __shfl_xor(bv, off);
        const int oi = __shfl_xor(bi, off);
        if (ov > bv || (ov == bv && oi < bi)) { bv = ov; bi = oi; }
    }
    if (lane == 0) out[row] = (float)bi;
}

// ---------------------------------------------------------------------------
extern "C" void kernel_launch(void* const* d_in, const int* in_sizes, int n_in,
                              void* d_out, int out_size, void* d_ws, size_t ws_size,
                              hipStream_t stream)
{
    const float* x_obj = (const float*)d_in[0];
    const float* x_pred = (const float*)d_in[1];
    const int* rel = (const int*)d_in[2];
    const float* oe_w1 = (const float*)d_in[3];
    const float* oe_b1 = (const float*)d_in[4];
    const float* oe_w2 = (const float*)d_in[5];
    const float* oe_b2 = (const float*)d_in[6];
    const float* pe_w1 = (const float*)d_in[7];
    const float* pe_b1 = (const float*)d_in[8];
    const float* pe_w2 = (const float*)d_in[9];
    const float* pe_b2 = (const float*)d_in[10];
    const float* g_sn_w = (const float*)d_in[11];
    const float* g_sn_b = (const float*)d_in[12];
    const float* g_on_w = (const float*)d_in[13];
    const float* g_on_b = (const float*)d_in[14];
    const float* g_se_w = (const float*)d_in[15];
    const float* g_se_b = (const float*)d_in[16];
    const float* g_oe_w = (const float*)d_in[17];
    const float* g_oe_b = (const float*)d_in[18];
    const float* ngru_wih = (const float*)d_in[19];
    const float* ngru_whh = (const float*)d_in[20];
    const float* ngru_bih = (const float*)d_in[21];
    const float* ngru_bhh = (const float*)d_in[22];
    const float* egru_wih = (const float*)d_in[23];
    const float* egru_whh = (const float*)d_in[24];
    const float* egru_bih = (const float*)d_in[25];
    const float* egru_bhh = (const float*)d_in[26];
    const float* op_w = (const float*)d_in[27];
    const float* op_b = (const float*)d_in[28];
    const float* pp_w = (const float*)d_in[29];
    const float* pp_b = (const float*)d_in[30];

    float* out = (float*)d_out;

    float* h_obj = out + OFF_HOBJ;       // f32 state written only at final step
    float* h_edge = out + OFF_HEDGE;

    // ---- workspace layout ----
    char* wsp = (char*)d_ws;
    float* af = (float*)wsp; wsp += N_RELS * 4;
    float* ag = (float*)wsp; wsp += N_RELS * 4;
    int* cs = (int*)wsp;   wsp += N_OBJS * 4;
    int* co = (int*)wsp;   wsp += N_OBJS * 4;
    int* offs = (int*)wsp; wsp += N_OBJS * 4;
    int* offo = (int*)wsp; wsp += N_OBJS * 4;
    int* curS = (int*)wsp; wsp += N_OBJS * 4;
    int* curO = (int*)wsp; wsp += N_OBJS * 4;
    int* listS = (int*)wsp; wsp += N_RELS * 4;
    int* listO = (int*)wsp; wsp += N_RELS * 4;

    u16* wp = (u16*)wsp;
    const int s_big = DIM * D_IN, s_sq = DIM * DIM, s_gru = 3 * DIM * DIM;
    // weights (f16)
    u16 *oe1h = wp; wp += s_big;
    u16 *pe1h = wp; wp += s_big;
    u16 *oe2h = wp; wp += s_sq;
    u16 *pe2h = wp; wp += s_sq;
    u16 *nih_h = wp; wp += s_gru;
    u16 *nhh_h = wp; wp += s_gru;
    u16 *eih_h = wp; wp += s_gru;
    u16 *ehh_h = wp; wp += s_gru;
    u16 *oph = wp; wp += 256 * DIM;
    u16 *pph = wp; wp += 128 * DIM;
    // f16 activations
    u16 *tmpo_h = wp; wp += (size_t)N_OBJS * DIM;   // enc1-obj out hi
    u16 *tmpo_l = wp; wp += (size_t)N_OBJS * DIM;   // enc1-obj out lo
    u16 *tmpe_h = wp; wp += (size_t)N_RELS * DIM;   // enc1-edge out (1-term)
    u16 *hhoh = wp; wp += (size_t)N_OBJS * DIM;     // h_obj shadow hi
    u16 *hhol = wp; wp += (size_t)N_OBJS * DIM;     // h_obj shadow lo
    u16 *hhe  = wp; wp += (size_t)N_RELS * DIM;     // h_edge shadow (1-term)
    u16 *emh  = wp; wp += (size_t)N_RELS * DIM;     // edge messages f16
    u16 *nmh  = wp; wp += (size_t)N_OBJS * DIM;     // node messages hi
    u16 *nml  = wp; wp += (size_t)N_OBJS * DIM;     // node messages lo

    // gi/gh chunk buffers (f16, R x 1536 each)
    const size_t used = (size_t)((char*)wp - (char*)d_ws);
    int R = 8192;
    if (used + (size_t)16384 * 6144 <= ws_size) R = 16384;
    u16* gi = wp;
    u16* gh = gi + (size_t)R * 1536;

    // all weight conversions in ONE launch
    convert_all<<<(CV_C9 + 255) / 256, 256, 0, stream>>>(
        oe_w1, oe1h, pe_w1, pe1h, oe_w2, oe2h, pe_w2, pe2h,
        ngru_wih, nih_h, ngru_whh, nhh_h, egru_wih, eih_h, egru_whh, ehh_h,
        op_w, oph, pp_w, pph);

    // CSR build (+ rel_inds passthrough folded into fill_csr)
    hipMemsetAsync(cs, 0, 2 * N_OBJS * sizeof(int), stream);
    hipMemsetAsync(curS, 0, 2 * N_OBJS * sizeof(int), stream);
    count_int<<<N_RELS / 256, 256, 0, stream>>>(rel, cs, co);
    scan_off<<<1, 256, 0, stream>>>(cs, co, offs, offo);
    fill_csr<<<N_RELS / 256, 256, 0, stream>>>(rel, curS, curO, offs, offo,
                                               listS, listO, out + OFF_RI);

    // enc1: FUSED edge(1-term) + obj(2-term split-out) in one launch
    enc1_both<<<1088, 256, 0, stream>>>(
        x_pred, pe1h, pe_b1, tmpe_h,
        x_obj, oe1h, oe_b1, tmpo_h, tmpo_l);
    // enc2: separate (preserves edge AT1 occupancy)
    gemm_f16<1, false, true, false><<<4 * (N_RELS / 128), 256, 0, stream>>>(
        tmpe_h, nullptr, pe2h, pe_b2, nullptr, hhe, nullptr, 4, DIM, DIM, DIM);
    gemm_f16<2, false, true, true><<<4 * (N_OBJS / 128), 256, 0, stream>>>(
        tmpo_h, tmpo_l, oe2h, oe_b2, nullptr, hhoh, hhol, 4, DIM, DIM, DIM);

    // message-passing steps (f16 state between steps; f32 out at last step)
    for (int step = 0; step < 2; step++) {
        gatepass<<<N_RELS / 4, 256, 0, stream>>>(
            hhoh, hhe, rel,
            g_sn_w, g_sn_b, g_on_w, g_on_b, g_se_w, g_se_b, g_oe_w, g_oe_b,
            cs, co, emh, af, ag);
        gather_nm<<<N_OBJS / 4, 256, 0, stream>>>(
            hhe, listS, listO, offs, offo, cs, co, af, ag, nmh, nml);

        // obj GRU (2-term)
        gru_gemm2<2><<<24 * (N_OBJS / 128), 256, 0, stream>>>(
            nmh, nml, nih_h, ngru_bih, gi, hhoh, hhol, nhh_h, ngru_bhh, gh, DIM);
        if (step == 0)
            gru_combine<true, false><<<(N_OBJS * 128 + 255) / 256, 256, 0, stream>>>(
                gi, gh, hhoh, hhol, nullptr, N_OBJS);
        else
            gru_combine<true, true><<<(N_OBJS * 128 + 255) / 256, 256, 0, stream>>>(
                gi, gh, hhoh, hhol, h_obj, N_OBJS);

        // edge GRU (1-term), chunked
        for (int r0 = 0; r0 < N_RELS; r0 += R) {
            const int Rc = (N_RELS - r0 < R) ? (N_RELS - r0) : R;
            gru_gemm2<1><<<24 * (Rc / 128), 256, 0, stream>>>(
                emh + (size_t)r0 * DIM, nullptr, eih_h, egru_bih, gi,
                hhe + (size_t)r0 * DIM, nullptr, ehh_h, egru_bhh, gh, DIM);
            if (step == 0)
                gru_combine<false, false><<<(Rc * 128 + 255) / 256, 256, 0, stream>>>(
                    gi, gh, hhe + (size_t)r0 * DIM, nullptr, nullptr, Rc);
            else
                gru_combine<false, true><<<(Rc * 128 + 255) / 256, 256, 0, stream>>>(
                    gi, gh, hhe + (size_t)r0 * DIM, nullptr, h_edge + (size_t)r0 * DIM, Rc);
        }
    }

    // classifiers: FUSED edge(1-term) + obj(2-term, labels) in one launch
    cls_both<<<288, 256, 0, stream>>>(
        hhe, pph, pp_b, out + OFF_PLOG,
        hhoh, hhol, oph, op_b, out + OFF_OLOG);

    // labels
    argmax_kernel<<<N_OBJS / 4, 256, 0, stream>>>(out + OFF_OLOG, out + OFF_LBL);
}

// Round 20
// 980.973 us; speedup vs baseline: 1.0512x; 1.0013x over previous
//
#include <hip/hip_runtime.h>
#include <math.h>

typedef unsigned short u16;
typedef unsigned int u32;
typedef _Float16 f16;
typedef f16 f16x8 __attribute__((ext_vector_type(8)));
typedef float f32x4 __attribute__((ext_vector_type(4)));

#define DIM 512
#define D_IN 4096
#define N_OBJS 2048
#define N_RELS 32768
#define N_OBJ_CLS 151
#define N_REL_CLS 51
#define EPSV 1e-5f

// d_out layout (floats)
#define OFF_HOBJ  0
#define OFF_HEDGE (N_OBJS*DIM)
#define OFF_OLOG  (OFF_HEDGE + N_RELS*DIM)
#define OFF_PLOG  (OFF_OLOG + N_OBJS*N_OBJ_CLS)
#define OFF_LBL   (OFF_PLOG + N_RELS*N_REL_CLS)
#define OFF_RI    (OFF_LBL + N_OBJS)

__device__ __forceinline__ float sigmoidf_(float x) { return 1.0f / (1.0f + expf(-x)); }
__device__ __forceinline__ u16 f2h_(float f) {
    union { f16 h; u16 u; } c; c.h = (f16)f; return c.u;
}
__device__ __forceinline__ float h2f_(u16 u) {
    union { f16 h; u16 u; } c; c.u = u; return (float)c.h;
}

// 8 fp32 -> packed f16 (uint4)
__device__ __forceinline__ void cvt8h1(const float* f, uint4& h) {
    u32 hh[8];
#pragma unroll
    for (int i = 0; i < 8; i++) hh[i] = f2h_(f[i]);
    h.x = hh[0] | (hh[1] << 16); h.y = hh[2] | (hh[3] << 16);
    h.z = hh[4] | (hh[5] << 16); h.w = hh[6] | (hh[7] << 16);
}
// 8 fp32 -> hi + lo (a ~= hi + lo)
__device__ __forceinline__ void cvt8h2(const float* f, uint4& h, uint4& l) {
    u32 hh[8], ll[8];
#pragma unroll
    for (int i = 0; i < 8; i++) {
        u16 x = f2h_(f[i]);
        hh[i] = x;
        ll[i] = f2h_(f[i] - h2f_(x));
    }
    h.x = hh[0] | (hh[1] << 16); h.y = hh[2] | (hh[3] << 16);
    h.z = hh[4] | (hh[5] << 16); h.w = hh[6] | (hh[7] << 16);
    l.x = ll[0] | (ll[1] << 16); l.y = ll[2] | (ll[3] << 16);
    l.z = ll[4] | (ll[5] << 16); l.w = ll[6] | (ll[7] << 16);
}

// LDS offset (u16 units) for (row, chunk8) in a [rows][32] tile, XOR-swizzled
__device__ __forceinline__ int swzo(int row, int c) {
    return row * 32 + ((c ^ ((row >> 1) & 3)) << 3);
}

// XCD-chunked bijective blockIdx swizzle (requires nwg % 8 == 0)
__device__ __forceinline__ int xcdswz(int orig, int nwg) {
    const int q = nwg >> 3;
    return (orig & 7) * q + (orig >> 3);
}

// async global->LDS, 16B per lane; LDS dest = wave-uniform base + lane*16
__device__ __forceinline__ void gload16(const void* g, void* l) {
    __builtin_amdgcn_global_load_lds(
        (const __attribute__((address_space(1))) void*)g,
        (__attribute__((address_space(3))) void*)l, 16, 0, 0);
}

// ---------------------------------------------------------------------------
// ONE-SHOT weight conversion: all 10 fp32 weight tensors -> f16 in a single
// launch. Segment boundaries are compile-time constants (quad = ushort4 units).
// ---------------------------------------------------------------------------
#define Q_BIG  (DIM * D_IN / 4)
#define Q_SQ   (DIM * DIM / 4)
#define Q_GRU  (3 * DIM * DIM / 4)
#define Q_OP   (N_OBJ_CLS * DIM / 4)
#define Q_PP   (N_REL_CLS * DIM / 4)
#define CV_C0  (Q_BIG)
#define CV_C1  (CV_C0 + Q_BIG)
#define CV_C2  (CV_C1 + Q_SQ)
#define CV_C3  (CV_C2 + Q_SQ)
#define CV_C4  (CV_C3 + Q_GRU)
#define CV_C5  (CV_C4 + Q_GRU)
#define CV_C6  (CV_C5 + Q_GRU)
#define CV_C7  (CV_C6 + Q_GRU)
#define CV_C8  (CV_C7 + Q_OP)
#define CV_C9  (CV_C8 + Q_PP)

__global__ __launch_bounds__(256) void convert_all(
    const float* __restrict__ s0, u16* __restrict__ d0,
    const float* __restrict__ s1, u16* __restrict__ d1,
    const float* __restrict__ s2, u16* __restrict__ d2,
    const float* __restrict__ s3, u16* __restrict__ d3,
    const float* __restrict__ s4, u16* __restrict__ d4,
    const float* __restrict__ s5, u16* __restrict__ d5,
    const float* __restrict__ s6, u16* __restrict__ d6,
    const float* __restrict__ s7, u16* __restrict__ d7,
    const float* __restrict__ s8, u16* __restrict__ d8,
    const float* __restrict__ s9, u16* __restrict__ d9)
{
    int i = blockIdx.x * 256 + threadIdx.x;
    if (i >= CV_C9) return;
    const float* src; u16* dst; int base;
    if      (i < CV_C0) { src = s0; dst = d0; base = 0; }
    else if (i < CV_C1) { src = s1; dst = d1; base = CV_C0; }
    else if (i < CV_C2) { src = s2; dst = d2; base = CV_C1; }
    else if (i < CV_C3) { src = s3; dst = d3; base = CV_C2; }
    else if (i < CV_C4) { src = s4; dst = d4; base = CV_C3; }
    else if (i < CV_C5) { src = s5; dst = d5; base = CV_C4; }
    else if (i < CV_C6) { src = s6; dst = d6; base = CV_C5; }
    else if (i < CV_C7) { src = s7; dst = d7; base = CV_C6; }
    else if (i < CV_C8) { src = s8; dst = d8; base = CV_C7; }
    else                { src = s9; dst = d9; base = CV_C8; }
    const int q = i - base;
    const float4 v = ((const float4*)src)[q];
    ((ushort4*)dst)[q] = make_ushort4(f2h_(v.x), f2h_(v.y), f2h_(v.z), f2h_(v.w));
}

// ---------------------------------------------------------------------------
// BODY: f16 GEMM, fp32 A split on the fly (AT terms), 1-deep A-reg prefetch,
// B f16 via global_load_lds. Caller provides LDS. BK=32, N = NX*128 exact.
// ---------------------------------------------------------------------------
template<bool RELU, int AT, bool WSPLIT>
__device__ __forceinline__ void gemm_a32_body(
    int id, u16* sAh, u16* sBh, u16* sAl,
    const float* __restrict__ A, const u16* __restrict__ Bhi,
    const float* __restrict__ bias, u16* __restrict__ Chi, u16* __restrict__ Clo,
    int NX, int K)
{
    const int m0 = (id / NX) * 128, n0 = (id % NX) * 128;
    const int N = NX * 128;
    const int t = threadIdx.x;
    const int wid = t >> 6, lane = t & 63;
    const int wm = (wid >> 1) * 64, wn = (wid & 1) * 64;
    const int lr = lane & 15, lk = lane >> 4;

    f32x4 acc[4][4] = {};

    const int sr = t >> 1;
    const int sc = (t & 1) * 2;
    const float* Ap = A + (size_t)(m0 + sr) * K + (t & 1) * 16;

    const int rB = (wid * 2) * 16 + (lane >> 2);
    const int cB = (lane & 3) ^ ((rB >> 1) & 3);
    const u16* Bp0 = Bhi + (size_t)(n0 + rB) * K + cB * 8;
    const u16* Bp1 = Bp0 + (size_t)16 * K;
    u16* Bd0 = &sBh[(wid * 2) * 512];
    u16* Bd1 = Bd0 + 512;

    float fv[16];
    *(float4*)&fv[0]  = *(const float4*)(Ap);
    *(float4*)&fv[4]  = *(const float4*)(Ap + 4);
    *(float4*)&fv[8]  = *(const float4*)(Ap + 8);
    *(float4*)&fv[12] = *(const float4*)(Ap + 12);

    for (int k0 = 0; k0 < K; k0 += 32) {
        uint4 ah0, ah1, al0, al1;
        if (AT == 2) { cvt8h2(fv, ah0, al0); cvt8h2(fv + 8, ah1, al1); }
        else         { cvt8h1(fv, ah0);      cvt8h1(fv + 8, ah1); }

        __syncthreads();                       // previous LDS reads complete
        gload16(Bp0 + k0, Bd0);
        gload16(Bp1 + k0, Bd1);
        *(uint4*)&sAh[swzo(sr, sc)]     = ah0;
        *(uint4*)&sAh[swzo(sr, sc + 1)] = ah1;
        if (AT == 2) {
            *(uint4*)&sAl[swzo(sr, sc)]     = al0;
            *(uint4*)&sAl[swzo(sr, sc + 1)] = al1;
        }
        asm volatile("s_waitcnt vmcnt(0)" ::: "memory");
        __syncthreads();

        const int kn = k0 + 32;
        if (kn < K) {
            *(float4*)&fv[0]  = *(const float4*)(Ap + kn);
            *(float4*)&fv[4]  = *(const float4*)(Ap + kn + 4);
            *(float4*)&fv[8]  = *(const float4*)(Ap + kn + 8);
            *(float4*)&fv[12] = *(const float4*)(Ap + kn + 12);
        }

        f16x8 ah[4], al[4], bh[4];
#pragma unroll
        for (int f = 0; f < 4; f++) {
            const int off = swzo(wm + f * 16 + lr, lk);
            ah[f] = *(const f16x8*)&sAh[off];
            if (AT == 2) al[f] = *(const f16x8*)&sAl[off];
            bh[f] = *(const f16x8*)&sBh[swzo(wn + f * 16 + lr, lk)];
        }
#pragma unroll
        for (int fm = 0; fm < 4; fm++)
#pragma unroll
            for (int fn = 0; fn < 4; fn++) {
                acc[fm][fn] = __builtin_amdgcn_mfma_f32_16x16x32_f16(ah[fm], bh[fn], acc[fm][fn], 0, 0, 0);
                if (AT == 2)
                    acc[fm][fn] = __builtin_amdgcn_mfma_f32_16x16x32_f16(al[fm], bh[fn], acc[fm][fn], 0, 0, 0);
            }
    }
#pragma unroll
    for (int fm = 0; fm < 4; fm++) {
        const int mrow = m0 + wm + fm * 16 + lk * 4;
#pragma unroll
        for (int fn = 0; fn < 4; fn++) {
            const int col = n0 + wn + fn * 16 + lr;
            const float bv = bias[col];
#pragma unroll
            for (int j = 0; j < 4; j++) {
                float v = acc[fm][fn][j] + bv;
                if (RELU) v = fmaxf(v, 0.0f);
                const u16 h = f2h_(v);
                Chi[(size_t)(mrow + j) * N + col] = h;
                if (WSPLIT) Clo[(size_t)(mrow + j) * N + col] = f2h_(v - h2f_(h));
            }
        }
    }
}

// FUSED enc1: ids [0,1024) = edge (AT1), ids [1024,1088) = obj (AT2, split out)
__global__ __launch_bounds__(256, 3) void enc1_both(
    const float* __restrict__ xp, const u16* __restrict__ pw,
    const float* __restrict__ pb, u16* __restrict__ tmpe,
    const float* __restrict__ xo, const u16* __restrict__ ow,
    const float* __restrict__ ob, u16* __restrict__ tmpoh, u16* __restrict__ tmpol)
{
    __shared__ u16 smem[3 * 4096];
    const int id = xcdswz(blockIdx.x, gridDim.x);
    if (id < 1024)
        gemm_a32_body<true, 1, false>(id, smem, smem + 4096, nullptr,
                                      xp, pw, pb, tmpe, nullptr, 4, D_IN);
    else
        gemm_a32_body<true, 2, true>(id - 1024, smem, smem + 4096, smem + 8192,
                                     xo, ow, ob, tmpoh, tmpol, 4, D_IN);
}

// ---------------------------------------------------------------------------
// BODY: f16 GEMM, A presplit (hi [+lo if AT=2]), B f16; all via gload_lds.
// BK=64. LDS: sA0=0, sA1=4096, sB0=8192, sB1=12288, [sL0=16384, sL1=20480].
// ---------------------------------------------------------------------------
template<int AT, bool WF32, bool WHI, bool WLO>
__device__ __forceinline__ void gemm_f16_body(
    int id, u16* smem,
    const u16* __restrict__ Ahi, const u16* __restrict__ Alo,
    const u16* __restrict__ Bhi, const float* __restrict__ bias,
    float* __restrict__ C32, u16* __restrict__ Chi, u16* __restrict__ Clo,
    int NX, int N, int ldc, int K)
{
    const int m0 = (id / NX) * 128, n0 = (id % NX) * 128;
    const int t = threadIdx.x;
    const int wid = t >> 6, lane = t & 63;
    const int wm = (wid >> 1) * 64, wn = (wid & 1) * 64;
    const int lr = lane & 15, lk = lane >> 4;

    f32x4 acc[4][4] = {};

    const int rr = (wid * 2) * 16 + (lane >> 2);
    const int cc = (lane & 3) ^ ((rr >> 1) & 3);
    const u16* pA0 = Ahi + (size_t)(m0 + rr) * K + cc * 8;
    const u16* pA1 = pA0 + (size_t)16 * K;
    const u16* pL0 = (AT == 2) ? Alo + (size_t)(m0 + rr) * K + cc * 8 : nullptr;
    const u16* pL1 = (AT == 2) ? pL0 + (size_t)16 * K : nullptr;
    const u16* pB0 = Bhi + (size_t)(n0 + rr) * K + cc * 8;
    const u16* pB1 = pB0 + (size_t)16 * K;
    const int bOff = (wid * 2) * 512;

    for (int k0 = 0; k0 < K; k0 += 64) {
        __syncthreads();
#pragma unroll
        for (int h = 0; h < 2; h++) {
            const int kk = k0 + h * 32;
            u16* sA_ = smem + h * 4096;
            u16* sB_ = smem + 8192 + h * 4096;
            gload16(pA0 + kk, sA_ + bOff);
            gload16(pA1 + kk, sA_ + bOff + 512);
            if (AT == 2) {
                u16* sL_ = smem + 16384 + h * 4096;
                gload16(pL0 + kk, sL_ + bOff);
                gload16(pL1 + kk, sL_ + bOff + 512);
            }
            gload16(pB0 + kk, sB_ + bOff);
            gload16(pB1 + kk, sB_ + bOff + 512);
        }
        asm volatile("s_waitcnt vmcnt(0)" ::: "memory");
        __syncthreads();

#pragma unroll
        for (int h = 0; h < 2; h++) {
            const u16* sA_ = smem + h * 4096;
            const u16* sB_ = smem + 8192 + h * 4096;
            const u16* sL_ = smem + 16384 + h * 4096;
            f16x8 ah[4], al[4], bh[4];
#pragma unroll
            for (int f = 0; f < 4; f++) {
                const int off = swzo(wm + f * 16 + lr, lk);
                ah[f] = *(const f16x8*)&sA_[off];
                if (AT == 2) al[f] = *(const f16x8*)&sL_[off];
                bh[f] = *(const f16x8*)&sB_[swzo(wn + f * 16 + lr, lk)];
            }
#pragma unroll
            for (int fm = 0; fm < 4; fm++)
#pragma unroll
                for (int fn = 0; fn < 4; fn++) {
                    acc[fm][fn] = __builtin_amdgcn_mfma_f32_16x16x32_f16(ah[fm], bh[fn], acc[fm][fn], 0, 0, 0);
                    if (AT == 2)
                        acc[fm][fn] = __builtin_amdgcn_mfma_f32_16x16x32_f16(al[fm], bh[fn], acc[fm][fn], 0, 0, 0);
                }
        }
    }
#pragma unroll
    for (int fm = 0; fm < 4; fm++) {
        const int mrow = m0 + wm + fm * 16 + lk * 4;
#pragma unroll
        for (int fn = 0; fn < 4; fn++) {
            const int col = n0 + wn + fn * 16 + lr;
            const float bv = bias[col];
#pragma unroll
            for (int j = 0; j < 4; j++) {
                const float v = acc[fm][fn][j] + bv;
                if (WF32 && col < N) C32[(size_t)(mrow + j) * ldc + col] = v;
                if (WHI) {
                    const u16 h = f2h_(v);
                    Chi[(size_t)(mrow + j) * (NX * 128) + col] = h;
                    if (WLO)
                        Clo[(size_t)(mrow + j) * (NX * 128) + col] = f2h_(v - h2f_(h));
                }
            }
        }
    }
}

// Standalone presplit GEMM kernels (enc2)
template<int AT, bool WF32, bool WHI, bool WLO>
__global__ __launch_bounds__(256, AT == 1 ? 4 : 3) void gemm_f16(
    const u16* __restrict__ Ahi, const u16* __restrict__ Alo,
    const u16* __restrict__ Bhi, const float* __restrict__ bias,
    float* __restrict__ C32, u16* __restrict__ Chi, u16* __restrict__ Clo,
    int NX, int N, int ldc, int K)
{
    __shared__ u16 smem[AT == 2 ? 6 * 4096 : 4 * 4096];
    const int id = xcdswz(blockIdx.x, gridDim.x);
    gemm_f16_body<AT, WF32, WHI, WLO>(id, smem, Ahi, Alo, Bhi, bias,
                                      C32, Chi, Clo, NX, N, ldc, K);
}

// FUSED classifiers: ids [0,256) = edge cls (AT1), [256,288) = obj cls (AT2)
__global__ __launch_bounds__(256, 3) void cls_both(
    const u16* __restrict__ hhe, const u16* __restrict__ pph,
    const float* __restrict__ ppb, float* __restrict__ plog,
    const u16* __restrict__ hhoh, const u16* __restrict__ hhol,
    const u16* __restrict__ oph, const float* __restrict__ opb,
    float* __restrict__ olog)
{
    __shared__ u16 smem[6 * 4096];
    const int id = xcdswz(blockIdx.x, gridDim.x);
    if (id < 256)
        gemm_f16_body<1, true, false, false>(id, smem, hhe, nullptr, pph, ppb,
                                             plog, nullptr, nullptr,
                                             1, N_REL_CLS, N_REL_CLS, DIM);
    else
        gemm_f16_body<2, true, false, false>(id - 256, smem, hhoh, hhol, oph, opb,
                                             olog, nullptr, nullptr,
                                             2, N_OBJ_CLS, N_OBJ_CLS, DIM);
}

// ---------------------------------------------------------------------------
// Plain merged edge GRU GEMM (chunks after the first): AT=1, 32KB LDS.
// ---------------------------------------------------------------------------
__global__ __launch_bounds__(256, 4) void gru_gemm_e(
    const u16* __restrict__ Xh, const u16* __restrict__ WiH,
    const float* __restrict__ bi, u16* __restrict__ gi,
    const u16* __restrict__ Hh, const u16* __restrict__ WhH,
    const float* __restrict__ bhs, u16* __restrict__ gh_)
{
    __shared__ u16 smem[4 * 4096];
    const int id = xcdswz(blockIdx.x, gridDim.x);
    const int part = id % 24;
    const int m0b = id / 24;
    const bool isH = part >= 12;
    const int nblk = part - (isH ? 12 : 0);
    gemm_f16_body<1, false, true, false>(m0b * 12 + nblk, smem,
        isH ? Hh : Xh, nullptr, isH ? WhH : WiH, isH ? bhs : bi,
        nullptr, isH ? gh_ : gi, nullptr, 12, 1536, 1536, DIM);
}

// ---------------------------------------------------------------------------
// FUSED GRU chunk-1: ALL blocks AT1 / 32KB LDS (4 blocks/CU):
//   ids [0,nEdge)            edge GRU rows of chunk 1      -> gi/gh
//   ids [nEdge, nEdge+384)   obj GRU, hi-A pass (bias)     -> gioh/ghoh
//   ids [nEdge+384, +768)    obj GRU, lo-A pass (zero bias)-> giol/ghol
// 2-term obj GEMM = hi-pass + lo-pass, summed in f32 at combine.
// ---------------------------------------------------------------------------
__global__ __launch_bounds__(256, 4) void gru_all1(
    const u16* __restrict__ Xe, const u16* __restrict__ WeI,
    const float* __restrict__ beI, u16* __restrict__ geI,
    const u16* __restrict__ He, const u16* __restrict__ WeH,
    const float* __restrict__ beH, u16* __restrict__ geH,
    int nEdge,
    const u16* __restrict__ Xoh, const u16* __restrict__ Xol,
    const u16* __restrict__ Hoh, const u16* __restrict__ Hol,
    const u16* __restrict__ WoI, const u16* __restrict__ WoH,
    const float* __restrict__ boI, const float* __restrict__ boH,
    const float* __restrict__ zb,
    u16* __restrict__ gioh, u16* __restrict__ giol,
    u16* __restrict__ ghoh, u16* __restrict__ ghol)
{
    __shared__ u16 smem[4 * 4096];
    const int id = xcdswz(blockIdx.x, gridDim.x);
    if (id < nEdge) {
        const int part = id % 24;
        const int m0b = id / 24;
        const bool isH = part >= 12;
        const int nblk = part - (isH ? 12 : 0);
        gemm_f16_body<1, false, true, false>(m0b * 12 + nblk, smem,
            isH ? He : Xe, nullptr, isH ? WeH : WeI, isH ? beH : beI,
            nullptr, isH ? geH : geI, nullptr, 12, 1536, 1536, DIM);
    } else if (id < nEdge + 384) {
        const int oid = id - nEdge;
        const int part = oid % 24;
        const int m0b = oid / 24;
        const bool isH = part >= 12;
        const int nblk = part - (isH ? 12 : 0);
        gemm_f16_body<1, false, true, false>(m0b * 12 + nblk, smem,
            isH ? Hoh : Xoh, nullptr, isH ? WoH : WoI, isH ? boH : boI,
            nullptr, isH ? ghoh : gioh, nullptr, 12, 1536, 1536, DIM);
    } else {
        const int oid = id - nEdge - 384;
        const int part = oid % 24;
        const int m0b = oid / 24;
        const bool isH = part >= 12;
        const int nblk = part - (isH ? 12 : 0);
        gemm_f16_body<1, false, true, false>(m0b * 12 + nblk, smem,
            isH ? Hol : Xol, nullptr, isH ? WoH : WoI, zb,
            nullptr, isH ? ghol : giol, nullptr, 12, 1536, 1536, DIM);
    }
}

// ---------------------------------------------------------------------------
// GRU combine (edge, 1-term gates): gi/gh f16 [R x 1536]; h from f16 shadow.
// ---------------------------------------------------------------------------
__device__ __forceinline__ float gcomb(float ir, float iz, float in_,
                                       float hr, float hz, float hn, float h) {
    const float r = sigmoidf_(ir + hr);
    const float z = sigmoidf_(iz + hz);
    const float n = tanhf(in_ + r * hn);
    return (1.0f - z) * n + z * h;
}

template<bool WF32>
__global__ __launch_bounds__(256) void gru_combine(
    const u16* __restrict__ gi, const u16* __restrict__ gh,
    u16* __restrict__ hh, float* __restrict__ H32, int R)
{
    const int idx = blockIdx.x * 256 + threadIdx.x;      // R*128 quads
    if (idx >= R * 128) return;
    const int r = idx >> 7, c4 = (idx & 127) * 4;
    const size_t gb = (size_t)r * 1536 + c4;
    const ushort4 ir4 = *(const ushort4*)&gi[gb];
    const ushort4 iz4 = *(const ushort4*)&gi[gb + 512];
    const ushort4 in4 = *(const ushort4*)&gi[gb + 1024];
    const ushort4 hr4 = *(const ushort4*)&gh[gb];
    const ushort4 hz4 = *(const ushort4*)&gh[gb + 512];
    const ushort4 hn4 = *(const ushort4*)&gh[gb + 1024];
    const size_t hb = (size_t)r * 512 + c4;
    const ushort4 hhi = *(const ushort4*)&hh[hb];
    float4 o;
    o.x = gcomb(h2f_(ir4.x), h2f_(iz4.x), h2f_(in4.x),
                h2f_(hr4.x), h2f_(hz4.x), h2f_(hn4.x), h2f_(hhi.x));
    o.y = gcomb(h2f_(ir4.y), h2f_(iz4.y), h2f_(in4.y),
                h2f_(hr4.y), h2f_(hz4.y), h2f_(hn4.y), h2f_(hhi.y));
    o.z = gcomb(h2f_(ir4.z), h2f_(iz4.z), h2f_(in4.z),
                h2f_(hr4.z), h2f_(hz4.z), h2f_(hn4.z), h2f_(hhi.z));
    o.w = gcomb(h2f_(ir4.w), h2f_(iz4.w), h2f_(in4.w),
                h2f_(hr4.w), h2f_(hz4.w), h2f_(hn4.w), h2f_(hhi.w));
    *(ushort4*)&hh[hb] = make_ushort4(f2h_(o.x), f2h_(o.y), f2h_(o.z), f2h_(o.w));
    if (WF32) *(float4*)&H32[hb] = o;
}

// ---------------------------------------------------------------------------
// GRU combine (obj, 2-pass gates): gates = hi + lo contributions summed in
// f32; h from hi+lo shadow; writes hi/lo shadow (+f32 state at last step).
// ---------------------------------------------------------------------------
template<bool WF32>
__global__ __launch_bounds__(256) void gru_combine_o2(
    const u16* __restrict__ gih, const u16* __restrict__ gil,
    const u16* __restrict__ ghh_, const u16* __restrict__ ghl_,
    u16* __restrict__ hh, u16* __restrict__ hl, float* __restrict__ H32, int R)
{
    const int idx = blockIdx.x * 256 + threadIdx.x;
    if (idx >= R * 128) return;
    const int r = idx >> 7, c4 = (idx & 127) * 4;
    const size_t gb = (size_t)r * 1536 + c4;
    ushort4 a, b;
    float ir[4], iz[4], in_[4], hr[4], hz[4], hn[4];
    a = *(const ushort4*)&gih[gb];        b = *(const ushort4*)&gil[gb];
    ir[0] = h2f_(a.x) + h2f_(b.x); ir[1] = h2f_(a.y) + h2f_(b.y);
    ir[2] = h2f_(a.z) + h2f_(b.z); ir[3] = h2f_(a.w) + h2f_(b.w);
    a = *(const ushort4*)&gih[gb + 512];  b = *(const ushort4*)&gil[gb + 512];
    iz[0] = h2f_(a.x) + h2f_(b.x); iz[1] = h2f_(a.y) + h2f_(b.y);
    iz[2] = h2f_(a.z) + h2f_(b.z); iz[3] = h2f_(a.w) + h2f_(b.w);
    a = *(const ushort4*)&gih[gb + 1024]; b = *(const ushort4*)&gil[gb + 1024];
    in_[0] = h2f_(a.x) + h2f_(b.x); in_[1] = h2f_(a.y) + h2f_(b.y);
    in_[2] = h2f_(a.z) + h2f_(b.z); in_[3] = h2f_(a.w) + h2f_(b.w);
    a = *(const ushort4*)&ghh_[gb];        b = *(const ushort4*)&ghl_[gb];
    hr[0] = h2f_(a.x) + h2f_(b.x); hr[1] = h2f_(a.y) + h2f_(b.y);
    hr[2] = h2f_(a.z) + h2f_(b.z); hr[3] = h2f_(a.w) + h2f_(b.w);
    a = *(const ushort4*)&ghh_[gb + 512];  b = *(const ushort4*)&ghl_[gb + 512];
    hz[0] = h2f_(a.x) + h2f_(b.x); hz[1] = h2f_(a.y) + h2f_(b.y);
    hz[2] = h2f_(a.z) + h2f_(b.z); hz[3] = h2f_(a.w) + h2f_(b.w);
    a = *(const ushort4*)&ghh_[gb + 1024]; b = *(const ushort4*)&ghl_[gb + 1024];
    hn[0] = h2f_(a.x) + h2f_(b.x); hn[1] = h2f_(a.y) + h2f_(b.y);
    hn[2] = h2f_(a.z) + h2f_(b.z); hn[3] = h2f_(a.w) + h2f_(b.w);

    const size_t hb = (size_t)r * 512 + c4;
    const ushort4 hhi = *(const ushort4*)&hh[hb];
    const ushort4 hlo = *(const ushort4*)&hl[hb];
    float h[4];
    h[0] = h2f_(hhi.x) + h2f_(hlo.x); h[1] = h2f_(hhi.y) + h2f_(hlo.y);
    h[2] = h2f_(hhi.z) + h2f_(hlo.z); h[3] = h2f_(hhi.w) + h2f_(hlo.w);

    float o[4];
#pragma unroll
    for (int j = 0; j < 4; j++)
        o[j] = gcomb(ir[j], iz[j], in_[j], hr[j], hz[j], hn[j], h[j]);

    const ushort4 hi4 = make_ushort4(f2h_(o[0]), f2h_(o[1]), f2h_(o[2]), f2h_(o[3]));
    *(ushort4*)&hh[hb] = hi4;
    *(ushort4*)&hl[hb] = make_ushort4(
        f2h_(o[0] - h2f_(hi4.x)), f2h_(o[1] - h2f_(hi4.y)),
        f2h_(o[2] - h2f_(hi4.z)), f2h_(o[3] - h2f_(hi4.w)));
    if (WF32) *(float4*)&H32[hb] = make_float4(o[0], o[1], o[2], o[3]);
}

// ---------------------------------------------------------------------------
// CSR build
// ---------------------------------------------------------------------------
__global__ __launch_bounds__(256) void count_int(const int* __restrict__ rel,
                                                 int* cs, int* co)
{
    const int e = blockIdx.x * 256 + threadIdx.x;
    atomicAdd(&cs[rel[2 * e]], 1);
    atomicAdd(&co[rel[2 * e + 1]], 1);
}

__global__ __launch_bounds__(256) void scan_off(const int* __restrict__ cs,
    const int* __restrict__ co, int* __restrict__ offs, int* __restrict__ offo)
{
    __shared__ int tmp[256];
    for (int arr = 0; arr < 2; arr++) {
        const int* c = arr ? co : cs;
        int* off = arr ? offo : offs;
        const int base = threadIdx.x * 8;
        int loc[8]; int s = 0;
#pragma unroll
        for (int j = 0; j < 8; j++) { loc[j] = c[base + j]; s += loc[j]; }
        tmp[threadIdx.x] = s;
        __syncthreads();
        for (int d = 1; d < 256; d <<= 1) {
            const int v = (threadIdx.x >= d) ? tmp[threadIdx.x - d] : 0;
            __syncthreads();
            tmp[threadIdx.x] += v;
            __syncthreads();
        }
        int p = tmp[threadIdx.x] - s;    // exclusive prefix
#pragma unroll
        for (int j = 0; j < 8; j++) { off[base + j] = p; p += loc[j]; }
        __syncthreads();
    }
}

// fill CSR lists + write rel_inds passthrough (float) in the same pass
__global__ __launch_bounds__(256) void fill_csr(const int* __restrict__ rel,
    int* curS, int* curO, const int* __restrict__ offs, const int* __restrict__ offo,
    int* __restrict__ listS, int* __restrict__ listO, float* __restrict__ outri)
{
    const int e = blockIdx.x * 256 + threadIdx.x;
    const int s = rel[2 * e], o = rel[2 * e + 1];
    const int i = atomicAdd(&curS[s], 1);
    listS[offs[s] + i] = e;
    const int j = atomicAdd(&curO[o], 1);
    listO[offo[o] + j] = e;
    outri[2 * e]     = (float)s;
    outri[2 * e + 1] = (float)o;
}

// ---------------------------------------------------------------------------
// Gates + edge messages, one WAVE per edge (no barrier, no atomics).
// ---------------------------------------------------------------------------
__global__ __launch_bounds__(256) void gatepass(
    const u16* __restrict__ hho, const u16* __restrict__ hhe,
    const int* __restrict__ rel,
    const float* __restrict__ wsn, const float* __restrict__ bsn,
    const float* __restrict__ won, const float* __restrict__ bon,
    const float* __restrict__ wse, const float* __restrict__ bse,
    const float* __restrict__ woe, const float* __restrict__ boe,
    const int* __restrict__ cs, const int* __restrict__ co,
    u16* __restrict__ emh, float* __restrict__ af, float* __restrict__ ag)
{
    const int e = blockIdx.x * 4 + (threadIdx.x >> 6);
    const int lane = threadIdx.x & 63;
    const int s = rel[2 * e], o = rel[2 * e + 1];
    const int c = lane * 8;

    const uint4 hsu = *(const uint4*)&hho[(size_t)s * DIM + c];
    const uint4 hou = *(const uint4*)&hho[(size_t)o * DIM + c];
    const uint4 heu = *(const uint4*)&hhe[(size_t)e * DIM + c];
    float hs[8], ho[8], he[8];
    hs[0] = h2f_((u16)hsu.x); hs[1] = h2f_((u16)(hsu.x >> 16));
    hs[2] = h2f_((u16)hsu.y); hs[3] = h2f_((u16)(hsu.y >> 16));
    hs[4] = h2f_((u16)hsu.z); hs[5] = h2f_((u16)(hsu.z >> 16));
    hs[6] = h2f_((u16)hsu.w); hs[7] = h2f_((u16)(hsu.w >> 16));
    ho[0] = h2f_((u16)hou.x); ho[1] = h2f_((u16)(hou.x >> 16));
    ho[2] = h2f_((u16)hou.y); ho[3] = h2f_((u16)(hou.y >> 16));
    ho[4] = h2f_((u16)hou.z); ho[5] = h2f_((u16)(hou.z >> 16));
    ho[6] = h2f_((u16)hou.w); ho[7] = h2f_((u16)(hou.w >> 16));
    he[0] = h2f_((u16)heu.x); he[1] = h2f_((u16)(heu.x >> 16));
    he[2] = h2f_((u16)heu.y); he[3] = h2f_((u16)(heu.y >> 16));
    he[4] = h2f_((u16)heu.z); he[5] = h2f_((u16)(heu.z >> 16));
    he[6] = h2f_((u16)heu.w); he[7] = h2f_((u16)(heu.w >> 16));

    float p0 = 0.f, p1 = 0.f, p2 = 0.f, p3 = 0.f;
#pragma unroll
    for (int q = 0; q < 2; q++) {
        const float4 w0v = *(const float4*)&wsn[c + q * 4];
        const float4 w0e = *(const float4*)&wsn[DIM + c + q * 4];
        const float4 w1v = *(const float4*)&won[c + q * 4];
        const float4 w1e = *(const float4*)&won[DIM + c + q * 4];
        const float4 w2v = *(const float4*)&wse[c + q * 4];
        const float4 w2e = *(const float4*)&wse[DIM + c + q * 4];
        const float4 w3v = *(const float4*)&woe[c + q * 4];
        const float4 w3e = *(const float4*)&woe[DIM + c + q * 4];
        const float* s4 = &hs[q * 4];
        const float* o4 = &ho[q * 4];
        const float* e4 = &he[q * 4];
        p0 += s4[0]*w0v.x + s4[1]*w0v.y + s4[2]*w0v.z + s4[3]*w0v.w
            + e4[0]*w0e.x + e4[1]*w0e.y + e4[2]*w0e.z + e4[3]*w0e.w;
        p1 += o4[0]*w1v.x + o4[1]*w1v.y + o4[2]*w1v.z + o4[3]*w1v.w
            + e4[0]*w1e.x + e4[1]*w1e.y + e4[2]*w1e.z + e4[3]*w1e.w;
        p2 += s4[0]*w2v.x + s4[1]*w2v.y + s4[2]*w2v.z + s4[3]*w2v.w
            + e4[0]*w2e.x + e4[1]*w2e.y + e4[2]*w2e.z + e4[3]*w2e.w;
        p3 += o4[0]*w3v.x + o4[1]*w3v.y + o4[2]*w3v.z + o4[3]*w3v.w
            + e4[0]*w3e.x + e4[1]*w3e.y + e4[2]*w3e.z + e4[3]*w3e.w;
    }
#pragma unroll
    for (int off = 32; off; off >>= 1) {
        p0 += __shfl_xor(p0, off);
        p1 += __shfl_xor(p1, off);
        p2 += __shfl_xor(p2, off);
        p3 += __shfl_xor(p3, off);
    }
    const float gsn = sigmoidf_(p0 + bsn[0]);
    const float gon = sigmoidf_(p1 + bon[0]);
    const float gse = sigmoidf_(p2 + bse[0]);
    const float goe = sigmoidf_(p3 + boe[0]);

    if (lane == 0) {
        af[e] = 0.5f * gsn / ((float)cs[s] + EPSV);
        ag[e] = 0.5f * gon / ((float)co[o] + EPSV);
    }
    u16 em8[8];
#pragma unroll
    for (int j = 0; j < 8; j++)
        em8[j] = f2h_(0.5f * (gse * hs[j] + goe * ho[j]));
    *(uint4*)&emh[(size_t)e * DIM + c] = *(const uint4*)em8;
}

// ---------------------------------------------------------------------------
// Node-message gather (no atomics), reading f16 h_edge shadow.
// ---------------------------------------------------------------------------
__global__ __launch_bounds__(256) void gather_nm(
    const u16* __restrict__ hhe,
    const int* __restrict__ listS, const int* __restrict__ listO,
    const int* __restrict__ offs, const int* __restrict__ offo,
    const int* __restrict__ cs, const int* __restrict__ co,
    const float* __restrict__ af, const float* __restrict__ ag,
    u16* __restrict__ nmh, u16* __restrict__ nml)
{
    const int v = blockIdx.x * 4 + (threadIdx.x >> 6);
    const int lane = threadIdx.x & 63;
    const int c = lane * 8;

    float acc[8] = {};
#pragma unroll
    for (int side = 0; side < 2; side++) {
        const int* list = side ? listO : listS;
        const int b = side ? offo[v] : offs[v];
        const int n = side ? co[v] : cs[v];
        const float* coef = side ? ag : af;
        for (int i = 0; i < n; i++) {
            const int e = list[b + i];
            const float a = coef[e];
            const uint4 x = *(const uint4*)&hhe[(size_t)e * DIM + c];
            acc[0] += a * h2f_((u16)x.x); acc[1] += a * h2f_((u16)(x.x >> 16));
            acc[2] += a * h2f_((u16)x.y); acc[3] += a * h2f_((u16)(x.y >> 16));
            acc[4] += a * h2f_((u16)x.z); acc[5] += a * h2f_((u16)(x.z >> 16));
            acc[6] += a * h2f_((u16)x.w); acc[7] += a * h2f_((u16)(x.w >> 16));
        }
    }
    u16 hi8[8], lo8[8];
#pragma unroll
    for (int j = 0; j < 8; j++) {
        hi8[j] = f2h_(acc[j]);
        lo8[j] = f2h_(acc[j] - h2f_(hi8[j]));
    }
    *(uint4*)&nmh[(size_t)v * DIM + c] = *(const uint4*)hi8;
    *(uint4*)&nml[(size_t)v * DIM + c] = *(const uint4*)lo8;
}

// ---------------------------------------------------------------------------
__global__ __launch_bounds__(256) void argmax_kernel(const float* __restrict__ logits,
                                                     float* __restrict__ out)
{
    const int row = blockIdx.x * 4 + (threadIdx.x >> 6);
    const int lane = threadIdx.x & 63;
    float bv = -1e30f; int bi = 1;
    for (int j = 1 + lane; j < N_OBJ_CLS; j += 64) {
        const float v = logits[(size_t)row * N_OBJ_CLS + j];
        if (v > bv) { bv = v; bi = j; }
    }
#pragma unroll
    for (int off = 32; off; off >>= 1) {
        const float ov = __shfl_xor(bv, off);
        const int oi = __shfl_xor(bi, off);
        if (ov > bv || (ov == bv && oi < bi)) { bv = ov; bi = oi; }
    }
    if (lane == 0) out[row] = (float)bi;
}

// ---------------------------------------------------------------------------
extern "C" void kernel_launch(void* const* d_in, const int* in_sizes, int n_in,
                              void* d_out, int out_size, void* d_ws, size_t ws_size,
                              hipStream_t stream)
{
    const float* x_obj = (const float*)d_in[0];
    const float* x_pred = (const float*)d_in[1];
    const int* rel = (const int*)d_in[2];
    const float* oe_w1 = (const float*)d_in[3];
    const float* oe_b1 = (const float*)d_in[4];
    const float* oe_w2 = (const float*)d_in[5];
    const float* oe_b2 = (const float*)d_in[6];
    const float* pe_w1 = (const float*)d_in[7];
    const float* pe_b1 = (const float*)d_in[8];
    const float* pe_w2 = (const float*)d_in[9];
    const float* pe_b2 = (const float*)d_in[10];
    const float* g_sn_w = (const float*)d_in[11];
    const float* g_sn_b = (const float*)d_in[12];
    const float* g_on_w = (const float*)d_in[13];
    const float* g_on_b = (const float*)d_in[14];
    const float* g_se_w = (const float*)d_in[15];
    const float* g_se_b = (const float*)d_in[16];
    const float* g_oe_w = (const float*)d_in[17];
    const float* g_oe_b = (const float*)d_in[18];
    const float* ngru_wih = (const float*)d_in[19];
    const float* ngru_whh = (const float*)d_in[20];
    const float* ngru_bih = (const float*)d_in[21];
    const float* ngru_bhh = (const float*)d_in[22];
    const float* egru_wih = (const float*)d_in[23];
    const float* egru_whh = (const float*)d_in[24];
    const float* egru_bih = (const float*)d_in[25];
    const float* egru_bhh = (const float*)d_in[26];
    const float* op_w = (const float*)d_in[27];
    const float* op_b = (const float*)d_in[28];
    const float* pp_w = (const float*)d_in[29];
    const float* pp_b = (const float*)d_in[30];

    float* out = (float*)d_out;

    float* h_obj = out + OFF_HOBJ;       // f32 state written only at final step
    float* h_edge = out + OFF_HEDGE;

    // ---- workspace layout ----
    char* wsp = (char*)d_ws;
    float* af = (float*)wsp; wsp += N_RELS * 4;
    float* ag = (float*)wsp; wsp += N_RELS * 4;
    float* zbias = (float*)wsp; wsp += 1536 * 4;
    int* cs = (int*)wsp;   wsp += N_OBJS * 4;
    int* co = (int*)wsp;   wsp += N_OBJS * 4;
    int* offs = (int*)wsp; wsp += N_OBJS * 4;
    int* offo = (int*)wsp; wsp += N_OBJS * 4;
    int* curS = (int*)wsp; wsp += N_OBJS * 4;
    int* curO = (int*)wsp; wsp += N_OBJS * 4;
    int* listS = (int*)wsp; wsp += N_RELS * 4;
    int* listO = (int*)wsp; wsp += N_RELS * 4;

    u16* wp = (u16*)wsp;
    const int s_big = DIM * D_IN, s_sq = DIM * DIM, s_gru = 3 * DIM * DIM;
    // weights (f16)
    u16 *oe1h = wp; wp += s_big;
    u16 *pe1h = wp; wp += s_big;
    u16 *oe2h = wp; wp += s_sq;
    u16 *pe2h = wp; wp += s_sq;
    u16 *nih_h = wp; wp += s_gru;
    u16 *nhh_h = wp; wp += s_gru;
    u16 *eih_h = wp; wp += s_gru;
    u16 *ehh_h = wp; wp += s_gru;
    u16 *oph = wp; wp += 256 * DIM;
    u16 *pph = wp; wp += 128 * DIM;
    // f16 activations
    u16 *tmpo_h = wp; wp += (size_t)N_OBJS * DIM;   // enc1-obj out hi
    u16 *tmpo_l = wp; wp += (size_t)N_OBJS * DIM;   // enc1-obj out lo
    u16 *tmpe_h = wp; wp += (size_t)N_RELS * DIM;   // enc1-edge out (1-term)
    u16 *hhoh = wp; wp += (size_t)N_OBJS * DIM;     // h_obj shadow hi
    u16 *hhol = wp; wp += (size_t)N_OBJS * DIM;     // h_obj shadow lo
    u16 *hhe  = wp; wp += (size_t)N_RELS * DIM;     // h_edge shadow (1-term)
    u16 *emh  = wp; wp += (size_t)N_RELS * DIM;     // edge messages f16
    u16 *nmh  = wp; wp += (size_t)N_OBJS * DIM;     // node messages hi
    u16 *nml  = wp; wp += (size_t)N_OBJS * DIM;     // node messages lo
    // obj GRU gate buffers (hi/lo passes)
    u16 *gioh = wp; wp += (size_t)N_OBJS * 1536;
    u16 *giol = wp; wp += (size_t)N_OBJS * 1536;
    u16 *ghoh = wp; wp += (size_t)N_OBJS * 1536;
    u16 *ghol = wp; wp += (size_t)N_OBJS * 1536;

    // edge gi/gh chunk buffers (f16, R x 1536 each)
    const size_t used = (size_t)((char*)wp - (char*)d_ws);
    int R = 8192;
    if (used + (size_t)16384 * 6144 <= ws_size) R = 16384;
    u16* gi = wp;
    u16* gh = gi + (size_t)R * 1536;

    // all weight conversions in ONE launch
    convert_all<<<(CV_C9 + 255) / 256, 256, 0, stream>>>(
        oe_w1, oe1h, pe_w1, pe1h, oe_w2, oe2h, pe_w2, pe2h,
        ngru_wih, nih_h, ngru_whh, nhh_h, egru_wih, eih_h, egru_whh, ehh_h,
        op_w, oph, pp_w, pph);

    // CSR build (+ rel_inds passthrough folded into fill_csr) + zero bias
    hipMemsetAsync(cs, 0, 2 * N_OBJS * sizeof(int), stream);
    hipMemsetAsync(curS, 0, 2 * N_OBJS * sizeof(int), stream);
    hipMemsetAsync(zbias, 0, 1536 * sizeof(float), stream);
    count_int<<<N_RELS / 256, 256, 0, stream>>>(rel, cs, co);
    scan_off<<<1, 256, 0, stream>>>(cs, co, offs, offo);
    fill_csr<<<N_RELS / 256, 256, 0, stream>>>(rel, curS, curO, offs, offo,
                                               listS, listO, out + OFF_RI);

    // enc1: FUSED edge(1-term) + obj(2-term split-out) in one launch
    enc1_both<<<1088, 256, 0, stream>>>(
        x_pred, pe1h, pe_b1, tmpe_h,
        x_obj, oe1h, oe_b1, tmpo_h, tmpo_l);
    // enc2: separate (preserves edge AT1 occupancy)
    gemm_f16<1, false, true, false><<<4 * (N_RELS / 128), 256, 0, stream>>>(
        tmpe_h, nullptr, pe2h, pe_b2, nullptr, hhe, nullptr, 4, DIM, DIM, DIM);
    gemm_f16<2, false, true, true><<<4 * (N_OBJS / 128), 256, 0, stream>>>(
        tmpo_h, tmpo_l, oe2h, oe_b2, nullptr, hhoh, hhol, 4, DIM, DIM, DIM);

    // message-passing steps (f16 state between steps; f32 out at last step)
    for (int step = 0; step < 2; step++) {
        gatepass<<<N_RELS / 4, 256, 0, stream>>>(
            hhoh, hhe, rel,
            g_sn_w, g_sn_b, g_on_w, g_on_b, g_se_w, g_se_b, g_oe_w, g_oe_b,
            cs, co, emh, af, ag);
        gather_nm<<<N_OBJS / 4, 256, 0, stream>>>(
            hhe, listS, listO, offs, offo, cs, co, af, ag, nmh, nml);

        // chunk 0: FUSED edge GRU + obj GRU (hi/lo passes), ALL 32KB/AT1
        const int Rc0 = (N_RELS < R) ? N_RELS : R;
        const int nEdge = 24 * (Rc0 / 128);
        gru_all1<<<nEdge + 768, 256, 0, stream>>>(
            emh, eih_h, egru_bih, gi, hhe, ehh_h, egru_bhh, gh, nEdge,
            nmh, nml, hhoh, hhol, nih_h, nhh_h, ngru_bih, ngru_bhh, zbias,
            gioh, giol, ghoh, ghol);

        // obj combine (sums hi+lo gate contributions in f32)
        if (step == 0)
            gru_combine_o2<false><<<(N_OBJS * 128 + 255) / 256, 256, 0, stream>>>(
                gioh, giol, ghoh, ghol, hhoh, hhol, nullptr, N_OBJS);
        else
            gru_combine_o2<true><<<(N_OBJS * 128 + 255) / 256, 256, 0, stream>>>(
                gioh, giol, ghoh, ghol, hhoh, hhol, h_obj, N_OBJS);
        // edge combine chunk 0
        if (step == 0)
            gru_combine<false><<<(Rc0 * 128 + 255) / 256, 256, 0, stream>>>(
                gi, gh, hhe, nullptr, Rc0);
        else
            gru_combine<true><<<(Rc0 * 128 + 255) / 256, 256, 0, stream>>>(
                gi, gh, hhe, h_edge, Rc0);

        // remaining edge chunks (plain 32KB kernel)
        for (int r0 = Rc0; r0 < N_RELS; r0 += R) {
            const int Rc = (N_RELS - r0 < R) ? (N_RELS - r0) : R;
            gru_gemm_e<<<24 * (Rc / 128), 256, 0, stream>>>(
                emh + (size_t)r0 * DIM, eih_h, egru_bih, gi,
                hhe + (size_t)r0 * DIM, ehh_h, egru_bhh, gh);
            if (step == 0)
                gru_combine<false><<<(Rc * 128 + 255) / 256, 256, 0, stream>>>(
                    gi, gh, hhe + (size_t)r0 * DIM, nullptr, Rc);
            else
                gru_combine<true><<<(Rc * 128 + 255) / 256, 256, 0, stream>>>(
                    gi, gh, hhe + (size_t)r0 * DIM, h_edge + (size_t)r0 * DIM, Rc);
        }
    }

    // classifiers: FUSED edge(1-term) + obj(2-term, labels) in one launch
    cls_both<<<288, 256, 0, stream>>>(
        hhe, pph, pp_b, out + OFF_PLOG,
        hhoh, hhol, oph, op_b, out + OFF_OLOG);

    // labels
    argmax_kernel<<<N_OBJS / 4, 256, 0, stream>>>(out + OFF_OLOG, out + OFF_LBL);
}